// Round 1
// baseline (265.573 us; speedup 1.0000x reference)
//
#include <hip/hip_runtime.h>
#include <hip/hip_bf16.h>
#include <cstdint>

typedef __hip_bfloat16 BF;
typedef unsigned short ushort_t;
typedef __attribute__((ext_vector_type(8))) __bf16 bf16x8;
typedef __attribute__((ext_vector_type(4))) float f32x4;

// Inputs/outputs are fp32 (established empirically rounds 2-9: detect flag
// always f32; fp32 output stores passed). Internal tensors bf16.
__device__ __forceinline__ float bu2f(ushort_t u) {
  return __uint_as_float((unsigned)u << 16);
}
__device__ __forceinline__ unsigned pk2(float a, float b) {
  union { __hip_bfloat162 h; unsigned u; } c;
  c.h = __float22bfloat162_rn(make_float2(a, b));  // v_cvt_pk_bf16_f32
  return c.u;
}
__device__ __forceinline__ unsigned short f2bu(float f) {
  union { BF b; unsigned short u; } c; c.b = __float2bfloat16(f); return c.u;
}
__device__ __forceinline__ float b2f(BF x) { return __bfloat162float(x); }
// 16 fp32 -> 16 bf16 bit patterns (8 packed converts).
__device__ __forceinline__ void rd16f(const float* fp, ushort_t* out) {
#pragma unroll
  for (int j = 0; j < 16; j += 4) {
    float4 v = *(const float4*)(fp + j);
    ((unsigned*)out)[j / 2] = pk2(v.x, v.y);
    ((unsigned*)out)[j / 2 + 1] = pk2(v.z, v.w);
  }
}

#define QS 0.1803368801111f  // (1/8)*log2(e): folded into Q so attn uses exp2

// ---------------------------------------------------------------------------
// pre_k: fused [gfeat transpose+cvt] + [Q projection w/ RoPE].
// blocks [0,2048): gfT[bz][m][k] bf16 <- gfeat[bz][k][m] fp32.
// blocks [2048,2560): Q = RoPE(local @ Wq^T + bq) * QS, 64x64 tiles.
// ---------------------------------------------------------------------------
__global__ __launch_bounds__(256) void pre_k(const float* __restrict__ local,
                                             const float* __restrict__ gfeat,
                                             const float* __restrict__ Wq,
                                             const float* __restrict__ bq,
                                             BF* __restrict__ gfT,
                                             BF* __restrict__ Qb) {
  __shared__ __align__(16) ushort_t smem[2][64][72];
  const int t = threadIdx.x;
  if (blockIdx.x < 2048) {
    auto T = smem[0];
    const int g = blockIdx.x;  // 4 bz x 64 mt x 8 kt
    const int bz = g & 3, mt = (g >> 2) & 63, kt = g >> 8;
    {
      int krow = t >> 2, mg = t & 3;
      ushort_t vals[16];
      rd16f(gfeat + (size_t)bz * 512 * 4096 + (size_t)(kt * 64 + krow) * 4096 +
                mt * 64 + mg * 16,
            vals);
#pragma unroll
      for (int j = 0; j < 16; ++j) T[mg * 16 + j][krow] = vals[j];
    }
    __syncthreads();
    int mrow = t >> 2, kg = t & 3;
    uint4 a = *(const uint4*)&T[mrow][kg * 16];
    uint4 b = *(const uint4*)&T[mrow][kg * 16 + 8];
    size_t o = ((size_t)bz * 4096 + mt * 64 + mrow) * 512 + kt * 64 + kg * 16;
    *(uint4*)&gfT[o] = a;
    *(uint4*)&gfT[o + 8] = b;
    return;
  }
  // ---- Q projection ----
  auto As = smem[0];
  auto Bs = smem[1];
  const int bx = blockIdx.x - 2048;
  const int m0 = (bx & 63) * 64, n0 = (bx >> 6) * 64;
  const int w = t >> 6, lane = t & 63;
  const int quad = lane >> 4, l16 = lane & 15;

  f32x4 acc[4] = {};
  for (int k0 = 0; k0 < 512; k0 += 64) {
    __syncthreads();
    {
      int row = t >> 2, cg = t & 3;
      int kg = k0 + cg * 16;
      ushort_t vals[16];
      rd16f(local + (size_t)(m0 + row) * 512 + kg, vals);
      *(uint4*)&As[row][cg * 16] = *(uint4*)&vals[0];
      *(uint4*)&As[row][cg * 16 + 8] = *(uint4*)&vals[8];
      ushort_t bv[16];
      rd16f(Wq + (size_t)(n0 + row) * 512 + kg, bv);
      *(uint4*)&Bs[row][cg * 16] = *(uint4*)&bv[0];
      *(uint4*)&Bs[row][cg * 16 + 8] = *(uint4*)&bv[8];
    }
    __syncthreads();
#pragma unroll
    for (int kc = 0; kc < 2; ++kc) {
      bf16x8 af = *(const bf16x8*)&As[w * 16 + l16][kc * 32 + quad * 8];
#pragma unroll
      for (int nt = 0; nt < 4; ++nt) {
        bf16x8 bfv = *(const bf16x8*)&Bs[nt * 16 + l16][kc * 32 + quad * 8];
        acc[nt] = __builtin_amdgcn_mfma_f32_16x16x32_bf16(af, bfv, acc[nt], 0, 0, 0);
      }
    }
  }
  const int head = n0 >> 6;
#pragma unroll
  for (int r = 0; r < 4; ++r) {
    int mg = m0 + w * 16 + quad * 4 + r;
    int bb = mg >> 10, qi = mg & 1023;
    float x = (float)(qi & 31) * (1.f / 31.f);
    float y = (float)(qi >> 5) * (1.f / 31.f);
    size_t base = (((size_t)bb * 8 + head) * 1024 + qi) * 64;
#pragma unroll
    for (int j = 0; j < 2; ++j) {
      int c0 = j * 16 + l16;
      float t0 = acc[j][r] + bq[head * 64 + c0];
      float t1 = acc[j + 2][r] + bq[head * 64 + c0 + 32];
      float fr = __expf((float)c0 * (-9.210340371976184f / 32.f));
      float ax = x * fr, ay = y * fr;
      Qb[base + c0] = __float2bfloat16((t0 * __cosf(ax) - t1 * __sinf(ax)) * QS);
      Qb[base + c0 + 32] = __float2bfloat16((t1 * __cosf(ay) + t0 * __sinf(ay)) * QS);
    }
  }
}

// ---------------------------------------------------------------------------
// kv_k: fused K/V projection from pre-transposed bf16 gfT. 128x128 tile,
// 1D XCD-pinned grid. n0<512 -> K+RoPE(global); else V -> V^T via LDS bounce.
// ---------------------------------------------------------------------------
__global__ __launch_bounds__(256) void kv_k(const BF* __restrict__ gfT,
                                            const float* __restrict__ Wk,
                                            const float* __restrict__ Wv,
                                            const float* __restrict__ bk,
                                            const float* __restrict__ bv,
                                            BF* __restrict__ Kb,
                                            BF* __restrict__ VTb) {
  __shared__ __align__(16) ushort_t smem[2][128][72];
  auto As = smem[0];
  auto Bs = smem[1];
  const int tid = threadIdx.x;
  const int w = tid >> 6, lane = tid & 63;
  const int quad = lane >> 4, l16 = lane & 15;
  const int wm = w >> 1, wn = w & 1;
  const int g = blockIdx.x;
  const int a = g & 7, y = (g >> 3) & 7, bidx = g >> 6;
  const int m0 = ((bidx << 1) | (a & 1)) * 128;
  const int n0 = y * 128;
  const int bz = a >> 1;

  f32x4 acc[4][4] = {};
  for (int k0 = 0; k0 < 512; k0 += 64) {
    __syncthreads();
#pragma unroll
    for (int u = 0; u < 2; ++u) {  // A: bf16 row-major gfT, pure b128
      int unit = tid + u * 256;
      int row = unit >> 2, cg = unit & 3;
      const uint4* p = (const uint4*)(gfT + ((size_t)bz * 4096 + m0 + row) * 512 +
                                      k0 + cg * 16);
      *(uint4*)&As[row][cg * 16] = p[0];
      *(uint4*)&As[row][cg * 16 + 8] = p[1];
    }
#pragma unroll
    for (int u = 0; u < 2; ++u) {  // B: Wk or Wv (fp32)
      int unit = tid + u * 256;
      int row = unit >> 2, cg = unit & 3;
      const float* bsrc = (n0 >= 512) ? Wv : Wk;
      size_t nrow = (n0 >= 512) ? (n0 - 512 + row) : (n0 + row);
      ushort_t vals[16];
      rd16f(bsrc + nrow * 512 + k0 + cg * 16, vals);
      *(uint4*)&Bs[row][cg * 16] = *(uint4*)&vals[0];
      *(uint4*)&Bs[row][cg * 16 + 8] = *(uint4*)&vals[8];
    }
    __syncthreads();
#pragma unroll
    for (int kc = 0; kc < 2; ++kc) {
      bf16x8 af[4], bfv[4];
#pragma unroll
      for (int i = 0; i < 4; ++i) {
        af[i] = *(const bf16x8*)&As[wm * 64 + i * 16 + l16][kc * 32 + quad * 8];
        bfv[i] = *(const bf16x8*)&Bs[wn * 64 + i * 16 + l16][kc * 32 + quad * 8];
      }
#pragma unroll
      for (int mt = 0; mt < 4; ++mt)
#pragma unroll
        for (int nt = 0; nt < 4; ++nt)
          acc[mt][nt] = __builtin_amdgcn_mfma_f32_16x16x32_bf16(af[mt], bfv[nt], acc[mt][nt], 0, 0, 0);
    }
  }
  if (n0 < 512) {  // K + RoPE(global)
    const int head = (n0 + wn * 64) >> 6;
#pragma unroll
    for (int mt = 0; mt < 4; ++mt)
#pragma unroll
      for (int r = 0; r < 4; ++r) {
        int pg = m0 + wm * 64 + mt * 16 + quad * 4 + r;
        float x = (float)(pg & 63) * (1.f / 63.f);
        float yy = (float)(pg >> 6) * (1.f / 63.f);
        size_t base = (((size_t)bz * 8 + head) * 4096 + pg) * 64;
#pragma unroll
        for (int j = 0; j < 2; ++j) {
          int c0 = j * 16 + l16;
          float t0 = acc[mt][j][r] + bk[head * 64 + c0];
          float t1 = acc[mt][j + 2][r] + bk[head * 64 + c0 + 32];
          float fr = __expf((float)c0 * (-9.210340371976184f / 32.f));
          float ax = x * fr, ay = yy * fr;
          Kb[base + c0] = __float2bfloat16(t0 * __cosf(ax) - t1 * __sinf(ax));
          Kb[base + c0 + 32] = __float2bfloat16(t1 * __cosf(ay) + t0 * __sinf(ay));
        }
      }
  } else {  // V -> V^T via LDS-bounce
    const int n0v = n0 - 512;
    __syncthreads();
    ushort_t (*T)[136] = (ushort_t(*)[136]) & smem[0][0][0];
#pragma unroll
    for (int mt = 0; mt < 4; ++mt)
#pragma unroll
      for (int nt = 0; nt < 4; ++nt)
#pragma unroll
        for (int r = 0; r < 4; ++r) {
          int n_l = wn * 64 + nt * 16 + l16;
          int m_l = wm * 64 + mt * 16 + quad * 4 + r;
          T[n_l][m_l] = f2bu(acc[mt][nt][r] + bv[n0v + n_l]);
        }
    __syncthreads();
    int row = tid >> 1, half = tid & 1;
    size_t gbase = (((size_t)bz * 8 + (n0v >> 6) + (row >> 6)) * 64 + (row & 63)) * 4096 +
                   m0 + half * 64;
    uint4* dst = (uint4*)(VTb + gbase);
    const uint4* src = (const uint4*)&T[row][half * 64];
#pragma unroll
    for (int j = 0; j < 8; ++j) dst[j] = src[j];
  }
}

// ---------------------------------------------------------------------------
// MFMA flash attention (round-8 v5 structure + round-10 LDS XOR swizzle).
// LDS-staged K/V chunks (block-wide broadcast; round-9 proved direct-L2 reads
// cost 4x L2 traffic). Transposed algebra: S^T=mfma(kb,qa), O^T=mfma(vb,pa),
// l=mfma(ones,pa). m=0 softmax, exp2 (scale folded into Q). Register
// prefetch of next chunk. Packed bf16 converts.
// Round-10: unpadded [64][64] tiles + 16B-chunk XOR swizzle (chunk ^= row&7)
// on Ks/VTs/Ps. The old [64][72] padding left 8 lanes stacked per 4-bank span
// on every ds_read_b128 (7.34M SQ_LDS_BANK_CONFLICT/dispatch); the swizzle
// puts reads/writes at the structural bank-phase floor and shrinks LDS
// 36.8KB -> 32KB. Same values, different LDS placement -> bit-identical.
// s_setprio(1) wraps the MFMA clusters (T5, +4-7% on attn per m191).
// ---------------------------------------------------------------------------
template <int NS>
__global__ __launch_bounds__(256) void attn_k(const BF* __restrict__ Q,
                                              const BF* __restrict__ K,
                                              const BF* __restrict__ VT,
                                              BF* __restrict__ AO,
                                              BF* __restrict__ Opart,
                                              float* __restrict__ lpart) {
  __shared__ __align__(16) ushort_t Ks[64][64];
  __shared__ __align__(16) ushort_t VTs[64][64];
  __shared__ __align__(16) ushort_t Ps[4][32][64];

  const int tid = threadIdx.x;
  const int w = tid >> 6, lane = tid & 63;
  const int quad = lane >> 4, l16 = lane & 15;
  // Swizzle: element chunk c (16B) of row r lives at chunk c ^ (r & 7).
  // All hot rows are (16k + l16), so row&7 == l16&7 (loop-invariant).
  const int r3 = l16 & 7;
  const int sc0 = (quad ^ r3) << 3;  // swizzled element col of orig chunk `quad`
  const int sc1 = sc0 ^ 32;          // orig chunk quad+4

  const int g = blockIdx.x;
  const int bh = g & 31;               // XCD = bh % 8 (K/V L2-pinned)
  const int qt = (g >> 5) & 7;
  const int ks = g >> 8;
  const int b = bh >> 3, h = bh & 7;
  const int q0 = qt * 128 + w * 32;
  const int kspan = 4096 / NS, kbase = ks * kspan;

  bf16x8 qa[2][2];
#pragma unroll
  for (int qs = 0; qs < 2; ++qs) {
    const BF* qp = Q + (((size_t)bh << 10) + q0 + qs * 16 + l16) * 64 + quad * 8;
    qa[qs][0] = *(const bf16x8*)qp;
    qa[qs][1] = *(const bf16x8*)(qp + 32);
  }
  bf16x8 ones;
#pragma unroll
  for (int j = 0; j < 8; ++j) ones[j] = (__bf16)1.0f;

  const BF* Kp = K + (size_t)bh * 4096 * 64;    // [key][dh]
  const BF* VTp = VT + (size_t)bh * 64 * 4096;  // [dh][key]

  f32x4 o[2][4] = {};
  f32x4 ol[2] = {};

  const int srow = tid >> 2, scol = (tid & 3) * 16;
  const int ssc = ((2 * (tid & 3)) ^ (srow & 7)) << 3;  // swizzled store col
  {  // stage first chunk
    const uint4* kp = (const uint4*)(Kp + (size_t)(kbase + srow) * 64 + scol);
    const uint4* vp = (const uint4*)(VTp + (size_t)srow * 4096 + kbase + scol);
    uint4 a = kp[0], bb = kp[1], c = vp[0], d = vp[1];
    *(uint4*)&Ks[srow][ssc] = a;  *(uint4*)&Ks[srow][ssc ^ 8] = bb;
    *(uint4*)&VTs[srow][ssc] = c; *(uint4*)&VTs[srow][ssc ^ 8] = d;
  }

  for (int c0k = kbase; c0k < kbase + kspan; c0k += 64) {
    __syncthreads();
    uint4 nk0, nk1, nv0, nv1;
    const bool more = (c0k + 64 < kbase + kspan);
    if (more) {  // register prefetch of next chunk
      const uint4* kp = (const uint4*)(Kp + (size_t)(c0k + 64 + srow) * 64 + scol);
      const uint4* vp = (const uint4*)(VTp + (size_t)srow * 4096 + c0k + 64 + scol);
      nk0 = kp[0]; nk1 = kp[1]; nv0 = vp[0]; nv1 = vp[1];
    }

    // ---- S^T = K Q^T ; P = exp2(S^T); packed b64 writes (swizzled) ----
#pragma unroll
    for (int ct = 0; ct < 4; ++ct) {
      const int krow = ct * 16 + l16;
      bf16x8 kb0 = *(const bf16x8*)&Ks[krow][sc0];
      bf16x8 kb1 = *(const bf16x8*)&Ks[krow][sc1];
#pragma unroll
      for (int qs = 0; qs < 2; ++qs) {
        f32x4 s = {};
        __builtin_amdgcn_s_setprio(1);
        s = __builtin_amdgcn_mfma_f32_16x16x32_bf16(kb0, qa[qs][0], s, 0, 0, 0);
        s = __builtin_amdgcn_mfma_f32_16x16x32_bf16(kb1, qa[qs][1], s, 0, 0, 0);
        __builtin_amdgcn_s_setprio(0);
        uint2 uu;
        uu.x = pk2(__builtin_exp2f(s[0]), __builtin_exp2f(s[1]));
        uu.y = pk2(__builtin_exp2f(s[2]), __builtin_exp2f(s[3]));
        *(uint2*)&Ps[w][qs * 16 + l16][(ct * 16 + quad * 4) ^ (r3 << 3)] = uu;
      }
    }

    // ---- O^T += V^T P^T ; l += 1^T P^T ----
#pragma unroll
    for (int qs = 0; qs < 2; ++qs) {
      const ushort_t* pr = &Ps[w][qs * 16 + l16][0];
      bf16x8 pa0 = *(const bf16x8*)(pr + sc0);
      bf16x8 pa1 = *(const bf16x8*)(pr + sc1);
      __builtin_amdgcn_s_setprio(1);
      ol[qs] = __builtin_amdgcn_mfma_f32_16x16x32_bf16(ones, pa0, ol[qs], 0, 0, 0);
      ol[qs] = __builtin_amdgcn_mfma_f32_16x16x32_bf16(ones, pa1, ol[qs], 0, 0, 0);
#pragma unroll
      for (int nt = 0; nt < 4; ++nt) {
        const int vrow = nt * 16 + l16;
        bf16x8 vb0 = *(const bf16x8*)&VTs[vrow][sc0];
        bf16x8 vb1 = *(const bf16x8*)&VTs[vrow][sc1];
        o[qs][nt] = __builtin_amdgcn_mfma_f32_16x16x32_bf16(vb0, pa0, o[qs][nt], 0, 0, 0);
        o[qs][nt] = __builtin_amdgcn_mfma_f32_16x16x32_bf16(vb1, pa1, o[qs][nt], 0, 0, 0);
      }
      __builtin_amdgcn_s_setprio(0);
    }

    __syncthreads();
    if (more) {
      *(uint4*)&Ks[srow][ssc] = nk0;  *(uint4*)&Ks[srow][ssc ^ 8] = nk1;
      *(uint4*)&VTs[srow][ssc] = nv0; *(uint4*)&VTs[srow][ssc ^ 8] = nv1;
    }
  }

  // ---- epilogue: lane holds O^T[dh = nt*16+quad*4+r][q = l16] ----
#pragma unroll
  for (int qs = 0; qs < 2; ++qs) {
    int qg = q0 + qs * 16 + l16;
    if (NS == 1) {
      float invl = 1.f / ol[qs][0];
#pragma unroll
      for (int nt = 0; nt < 4; ++nt) {
        uint2 uu;
        uu.x = pk2(o[qs][nt][0] * invl, o[qs][nt][1] * invl);
        uu.y = pk2(o[qs][nt][2] * invl, o[qs][nt][3] * invl);
        *(uint2*)(AO + (((size_t)b << 10) + qg) * 512 + h * 64 + nt * 16 + quad * 4) = uu;
      }
    } else {
      if (quad == 0) lpart[ks * 32768 + (bh << 10) + qg] = ol[qs][0];
#pragma unroll
      for (int nt = 0; nt < 4; ++nt) {
        uint2 uu;
        uu.x = pk2(o[qs][nt][0], o[qs][nt][1]);
        uu.y = pk2(o[qs][nt][2], o[qs][nt][3]);
        *(uint2*)(Opart + (size_t)ks * 2097152 + (((size_t)bh << 10) + qg) * 64 +
                  nt * 16 + quad * 4) = uu;
      }
    }
  }
}

// ---------------------------------------------------------------------------
// gate_k: gate GEMM (K=1024, A=[local | AO]) + sigmoid-gate epilogue.
// The NS-way K-split merge is FUSED into A-staging (kg>=512 path reads
// Opart/lpart and merges inline) — no reduce_k launch, no AO roundtrip.
// The AO tile needed by the epilogue is captured from LDS at k0==512+n0.
// ---------------------------------------------------------------------------
template <int NS>
__global__ __launch_bounds__(256) void gate_k(const float* __restrict__ local,
                                              const BF* __restrict__ AO,
                                              const BF* __restrict__ Opart,
                                              const float* __restrict__ lpart,
                                              const float* __restrict__ Wg,
                                              const float* __restrict__ bg,
                                              BF* __restrict__ ENH) {
  __shared__ __align__(16) ushort_t As[64][72];
  __shared__ __align__(16) ushort_t Bs[64][72];
  const int tid = threadIdx.x;
  const int w = tid >> 6, lane = tid & 63;
  const int quad = lane >> 4, l16 = lane & 15;
  const int m0 = blockIdx.x * 64, n0 = blockIdx.y * 64;

  f32x4 acc[4] = {};
  float aosv[4][4];  // AO values for epilogue, captured from As
  for (int k0 = 0; k0 < 1024; k0 += 64) {
    __syncthreads();
    {
      int row = tid >> 2, cg = tid & 3;
      int kg = k0 + cg * 16;
      ushort_t vals[16];
      if (kg < 512) {
        rd16f(local + (size_t)(m0 + row) * 512 + kg, vals);
      } else {
        int c = kg - 512;               // 16-aligned, single head per unit
        int hh = c >> 6, dh0 = c & 63;
        int mg = m0 + row;
        size_t bq = (size_t)(((mg >> 10) * 8 + hh) << 10) + (mg & 1023);
        if (NS == 1) {
          const uint4* p = (const uint4*)(AO + (size_t)mg * 512 + c);
          *(uint4*)&vals[0] = p[0]; *(uint4*)&vals[8] = p[1];
        } else {
          float ls = 0.f;
#pragma unroll
          for (int s2 = 0; s2 < NS; ++s2) ls += lpart[s2 * 32768 + bq];
          float inv = 1.f / ls;
          float av[16] = {};
#pragma unroll
          for (int s2 = 0; s2 < NS; ++s2) {
            const ushort_t* op = (const ushort_t*)Opart + (size_t)s2 * 2097152 +
                                 bq * 64 + dh0;
            uint4 u0 = ((const uint4*)op)[0], u1 = ((const uint4*)op)[1];
            const ushort_t* pu = (const ushort_t*)&u0;
#pragma unroll
            for (int j = 0; j < 8; ++j) av[j] += bu2f(pu[j]);
            pu = (const ushort_t*)&u1;
#pragma unroll
            for (int j = 0; j < 8; ++j) av[8 + j] += bu2f(pu[j]);
          }
#pragma unroll
          for (int j = 0; j < 16; j += 2)
            ((unsigned*)vals)[j / 2] = pk2(av[j] * inv, av[j + 1] * inv);
        }
      }
      *(uint4*)&As[row][cg * 16] = *(uint4*)&vals[0];
      *(uint4*)&As[row][cg * 16 + 8] = *(uint4*)&vals[8];
      ushort_t bv[16];
      rd16f(Wg + (size_t)(n0 + row) * 1024 + kg, bv);
      *(uint4*)&Bs[row][cg * 16] = *(uint4*)&bv[0];
      *(uint4*)&Bs[row][cg * 16 + 8] = *(uint4*)&bv[8];
    }
    __syncthreads();
    if (k0 == 512 + n0) {  // capture this block's AO tile for the epilogue
#pragma unroll
      for (int r = 0; r < 4; ++r)
#pragma unroll
        for (int nt = 0; nt < 4; ++nt)
          aosv[r][nt] = bu2f(As[w * 16 + quad * 4 + r][nt * 16 + l16]);
    }
#pragma unroll
    for (int kc = 0; kc < 2; ++kc) {
      bf16x8 af = *(const bf16x8*)&As[w * 16 + l16][kc * 32 + quad * 8];
#pragma unroll
      for (int nt = 0; nt < 4; ++nt) {
        bf16x8 bfv = *(const bf16x8*)&Bs[nt * 16 + l16][kc * 32 + quad * 8];
        acc[nt] = __builtin_amdgcn_mfma_f32_16x16x32_bf16(af, bfv, acc[nt], 0, 0, 0);
      }
    }
  }
#pragma unroll
  for (int r = 0; r < 4; ++r) {
    int mg = m0 + w * 16 + quad * 4 + r;
#pragma unroll
    for (int nt = 0; nt < 4; ++nt) {
      int ng = n0 + nt * 16 + l16;
      size_t idx = (size_t)mg * 512 + ng;
      float gg = 1.f / (1.f + __expf(-(acc[nt][r] + bg[ng])));
      ENH[idx] = __float2bfloat16(local[idx] + gg * aosv[r][nt]);
    }
  }
}

// ---------------------------------------------------------------------------
// out_k: final projection, fp32 output.
// ---------------------------------------------------------------------------
__global__ __launch_bounds__(256) void out_k(const BF* __restrict__ ENH,
                                             const float* __restrict__ Wo,
                                             const float* __restrict__ bo,
                                             float* __restrict__ out) {
  __shared__ __align__(16) ushort_t As[64][72];
  __shared__ __align__(16) ushort_t Bs[64][72];
  const int tid = threadIdx.x;
  const int w = tid >> 6, lane = tid & 63;
  const int quad = lane >> 4, l16 = lane & 15;
  const int m0 = blockIdx.x * 64, n0 = blockIdx.y * 64;

  f32x4 acc[4] = {};
  for (int k0 = 0; k0 < 512; k0 += 64) {
    __syncthreads();
    {
      int row = tid >> 2, cg = tid & 3;
      int kg = k0 + cg * 16;
      const uint4* p = (const uint4*)(ENH + (size_t)(m0 + row) * 512 + kg);
      *(uint4*)&As[row][cg * 16] = p[0];
      *(uint4*)&As[row][cg * 16 + 8] = p[1];
      ushort_t bv[16];
      rd16f(Wo + (size_t)(n0 + row) * 512 + kg, bv);
      *(uint4*)&Bs[row][cg * 16] = *(uint4*)&bv[0];
      *(uint4*)&Bs[row][cg * 16 + 8] = *(uint4*)&bv[8];
    }
    __syncthreads();
#pragma unroll
    for (int kc = 0; kc < 2; ++kc) {
      bf16x8 af = *(const bf16x8*)&As[w * 16 + l16][kc * 32 + quad * 8];
#pragma unroll
      for (int nt = 0; nt < 4; ++nt) {
        bf16x8 bfv = *(const bf16x8*)&Bs[nt * 16 + l16][kc * 32 + quad * 8];
        acc[nt] = __builtin_amdgcn_mfma_f32_16x16x32_bf16(af, bfv, acc[nt], 0, 0, 0);
      }
    }
  }
#pragma unroll
  for (int r = 0; r < 4; ++r) {
    int mg = m0 + w * 16 + quad * 4 + r;
#pragma unroll
    for (int nt = 0; nt < 4; ++nt) {
      int ng = n0 + nt * 16 + l16;
      out[(size_t)mg * 512 + ng] = acc[nt][r] + bo[ng];
    }
  }
}

extern "C" void kernel_launch(void* const* d_in, const int* in_sizes, int n_in,
                              void* d_out, int out_size, void* d_ws, size_t ws_size,
                              hipStream_t stream) {
  const float* local = (const float*)d_in[0];
  const float* gfeat = (const float*)d_in[1];
  const float* Wq = (const float*)d_in[2];
  const float* bq = (const float*)d_in[3];
  const float* Wk = (const float*)d_in[4];
  const float* bk = (const float*)d_in[5];
  const float* Wv = (const float*)d_in[6];
  const float* bv = (const float*)d_in[7];
  const float* Wg = (const float*)d_in[8];
  const float* bg = (const float*)d_in[9];
  const float* Wo = (const float*)d_in[10];
  const float* bo = (const float*)d_in[11];

  char* w = (char*)d_ws;
  BF* Qb = (BF*)w;            w += (size_t)2097152 * 2;  // 4 MB (reused as ENH)
  BF* Kb = (BF*)w;            w += (size_t)8388608 * 2;  // 16 MB
  BF* VTb = (BF*)w;           w += (size_t)8388608 * 2;  // 16 MB (V^T [b,h,dh,key])
  BF* AO = (BF*)w;            w += (size_t)2097152 * 2;  // 4 MB (NS==1 only)
  // Region X: gfT (16 MB, dead after kv_k) aliases Opart (NS x 4 MB).
  BF* gfT = (BF*)w;
  BF* Opart = (BF*)w;
  size_t baseOff = (size_t)(w - (char*)d_ws);
  BF* ENH = Qb;

  int NS = 1;
  if (baseOff + 4 * (4194304 + 131072) <= ws_size) NS = 4;
  else if (baseOff + 16777216 + 2 * 131072 <= ws_size) NS = 2;
  float* lpart = (float*)(w + (size_t)NS * 4194304);

  dim3 blk(256);
  pre_k<<<dim3(2560), blk, 0, stream>>>(local, gfeat, Wq, bq, gfT, Qb);
  kv_k<<<dim3(1024), blk, 0, stream>>>(gfT, Wk, Wv, bk, bv, Kb, VTb);
  if (NS == 4) {
    attn_k<4><<<dim3(1024), blk, 0, stream>>>(Qb, Kb, VTb, AO, Opart, lpart);
    gate_k<4><<<dim3(64, 8), blk, 0, stream>>>(local, AO, Opart, lpart, Wg, bg, ENH);
  } else if (NS == 2) {
    attn_k<2><<<dim3(512), blk, 0, stream>>>(Qb, Kb, VTb, AO, Opart, lpart);
    gate_k<2><<<dim3(64, 8), blk, 0, stream>>>(local, AO, Opart, lpart, Wg, bg, ENH);
  } else {
    attn_k<1><<<dim3(256), blk, 0, stream>>>(Qb, Kb, VTb, AO, nullptr, nullptr);
    gate_k<1><<<dim3(64, 8), blk, 0, stream>>>(local, AO, Opart, lpart, Wg, bg, ENH);
  }
  out_k<<<dim3(64, 8), blk, 0, stream>>>(ENH, Wo, bo, (float*)d_out);
}

// Round 2
// 249.545 us; speedup vs baseline: 1.0642x; 1.0642x over previous
//
#include <hip/hip_runtime.h>
#include <hip/hip_bf16.h>
#include <cstdint>

typedef __hip_bfloat16 BF;
typedef unsigned short ushort_t;
typedef __attribute__((ext_vector_type(8))) __bf16 bf16x8;
typedef __attribute__((ext_vector_type(4))) float f32x4;
typedef __attribute__((ext_vector_type(2))) unsigned uv2;
typedef __attribute__((ext_vector_type(4))) unsigned uint4v;

// Inputs/outputs are fp32 (established empirically rounds 2-9: detect flag
// always f32; fp32 output stores passed). Internal tensors bf16.
__device__ __forceinline__ float bu2f(ushort_t u) {
  return __uint_as_float((unsigned)u << 16);
}
__device__ __forceinline__ unsigned pk2(float a, float b) {
  union { __hip_bfloat162 h; unsigned u; } c;
  c.h = __float22bfloat162_rn(make_float2(a, b));  // v_cvt_pk_bf16_f32
  return c.u;
}
__device__ __forceinline__ unsigned short f2bu(float f) {
  union { BF b; unsigned short u; } c; c.b = __float2bfloat16(f); return c.u;
}
__device__ __forceinline__ float b2f(BF x) { return __bfloat162float(x); }
// 16 fp32 -> 16 bf16 bit patterns (8 packed converts).
__device__ __forceinline__ void rd16f(const float* fp, ushort_t* out) {
#pragma unroll
  for (int j = 0; j < 16; j += 4) {
    float4 v = *(const float4*)(fp + j);
    ((unsigned*)out)[j / 2] = pk2(v.x, v.y);
    ((unsigned*)out)[j / 2 + 1] = pk2(v.z, v.w);
  }
}

// Quad-butterfly helpers for in-register P redistribution (round-11).
// qswapB5: exchange lanes 32-63 of a with lanes 0-31 of b (lane bit-5 stage).
__device__ __forceinline__ void qswapB5(unsigned& a, unsigned& b) {
  uv2 r = __builtin_amdgcn_permlane32_swap(a, b, false, false);
  a = r[0]; b = r[1];
}
// qswapB4: exchange 16-lane rows 1,3 of a with rows 0,2 of b (lane bit-4).
__device__ __forceinline__ void qswapB4(unsigned& a, unsigned& b, int lane) {
#if __has_builtin(__builtin_amdgcn_permlane16_swap)
  uv2 r = __builtin_amdgcn_permlane16_swap(a, b, false, false);
  a = r[0]; b = r[1];
#else
  unsigned as = __builtin_amdgcn_ds_swizzle(a, 0x401F);  // lane ^= 16
  unsigned bs = __builtin_amdgcn_ds_swizzle(b, 0x401F);
  bool hi = (lane & 16) != 0;
  unsigned na = hi ? bs : a;
  unsigned nb = hi ? b : as;
  a = na; b = nb;
#endif
}

#define QS 0.1803368801111f  // (1/8)*log2(e): folded into Q so attn uses exp2

// ---------------------------------------------------------------------------
// pre_k: fused [gfeat transpose+cvt] + [Q projection w/ RoPE].
// blocks [0,2048): gfT[bz][m][k] bf16 <- gfeat[bz][k][m] fp32.
// blocks [2048,2560): Q = RoPE(local @ Wq^T + bq) * QS, 64x64 tiles.
// ---------------------------------------------------------------------------
__global__ __launch_bounds__(256) void pre_k(const float* __restrict__ local,
                                             const float* __restrict__ gfeat,
                                             const float* __restrict__ Wq,
                                             const float* __restrict__ bq,
                                             BF* __restrict__ gfT,
                                             BF* __restrict__ Qb) {
  __shared__ __align__(16) ushort_t smem[2][64][72];
  const int t = threadIdx.x;
  if (blockIdx.x < 2048) {
    auto T = smem[0];
    const int g = blockIdx.x;  // 4 bz x 64 mt x 8 kt
    const int bz = g & 3, mt = (g >> 2) & 63, kt = g >> 8;
    {
      int krow = t >> 2, mg = t & 3;
      ushort_t vals[16];
      rd16f(gfeat + (size_t)bz * 512 * 4096 + (size_t)(kt * 64 + krow) * 4096 +
                mt * 64 + mg * 16,
            vals);
#pragma unroll
      for (int j = 0; j < 16; ++j) T[mg * 16 + j][krow] = vals[j];
    }
    __syncthreads();
    int mrow = t >> 2, kg = t & 3;
    uint4 a = *(const uint4*)&T[mrow][kg * 16];
    uint4 b = *(const uint4*)&T[mrow][kg * 16 + 8];
    size_t o = ((size_t)bz * 4096 + mt * 64 + mrow) * 512 + kt * 64 + kg * 16;
    *(uint4*)&gfT[o] = a;
    *(uint4*)&gfT[o + 8] = b;
    return;
  }
  // ---- Q projection ----
  auto As = smem[0];
  auto Bs = smem[1];
  const int bx = blockIdx.x - 2048;
  const int m0 = (bx & 63) * 64, n0 = (bx >> 6) * 64;
  const int w = t >> 6, lane = t & 63;
  const int quad = lane >> 4, l16 = lane & 15;

  f32x4 acc[4] = {};
  for (int k0 = 0; k0 < 512; k0 += 64) {
    __syncthreads();
    {
      int row = t >> 2, cg = t & 3;
      int kg = k0 + cg * 16;
      ushort_t vals[16];
      rd16f(local + (size_t)(m0 + row) * 512 + kg, vals);
      *(uint4*)&As[row][cg * 16] = *(uint4*)&vals[0];
      *(uint4*)&As[row][cg * 16 + 8] = *(uint4*)&vals[8];
      ushort_t bv[16];
      rd16f(Wq + (size_t)(n0 + row) * 512 + kg, bv);
      *(uint4*)&Bs[row][cg * 16] = *(uint4*)&bv[0];
      *(uint4*)&Bs[row][cg * 16 + 8] = *(uint4*)&bv[8];
    }
    __syncthreads();
#pragma unroll
    for (int kc = 0; kc < 2; ++kc) {
      bf16x8 af = *(const bf16x8*)&As[w * 16 + l16][kc * 32 + quad * 8];
#pragma unroll
      for (int nt = 0; nt < 4; ++nt) {
        bf16x8 bfv = *(const bf16x8*)&Bs[nt * 16 + l16][kc * 32 + quad * 8];
        acc[nt] = __builtin_amdgcn_mfma_f32_16x16x32_bf16(af, bfv, acc[nt], 0, 0, 0);
      }
    }
  }
  const int head = n0 >> 6;
#pragma unroll
  for (int r = 0; r < 4; ++r) {
    int mg = m0 + w * 16 + quad * 4 + r;
    int bb = mg >> 10, qi = mg & 1023;
    float x = (float)(qi & 31) * (1.f / 31.f);
    float y = (float)(qi >> 5) * (1.f / 31.f);
    size_t base = (((size_t)bb * 8 + head) * 1024 + qi) * 64;
#pragma unroll
    for (int j = 0; j < 2; ++j) {
      int c0 = j * 16 + l16;
      float t0 = acc[j][r] + bq[head * 64 + c0];
      float t1 = acc[j + 2][r] + bq[head * 64 + c0 + 32];
      float fr = __expf((float)c0 * (-9.210340371976184f / 32.f));
      float ax = x * fr, ay = y * fr;
      Qb[base + c0] = __float2bfloat16((t0 * __cosf(ax) - t1 * __sinf(ax)) * QS);
      Qb[base + c0 + 32] = __float2bfloat16((t1 * __cosf(ay) + t0 * __sinf(ay)) * QS);
    }
  }
}

// ---------------------------------------------------------------------------
// kv_k: fused K/V projection from pre-transposed bf16 gfT. 128x128 tile,
// 1D XCD-pinned grid. n0<512 -> K+RoPE(global); else V -> V^T via LDS bounce.
// ---------------------------------------------------------------------------
__global__ __launch_bounds__(256) void kv_k(const BF* __restrict__ gfT,
                                            const float* __restrict__ Wk,
                                            const float* __restrict__ Wv,
                                            const float* __restrict__ bk,
                                            const float* __restrict__ bv,
                                            BF* __restrict__ Kb,
                                            BF* __restrict__ VTb) {
  __shared__ __align__(16) ushort_t smem[2][128][72];
  auto As = smem[0];
  auto Bs = smem[1];
  const int tid = threadIdx.x;
  const int w = tid >> 6, lane = tid & 63;
  const int quad = lane >> 4, l16 = lane & 15;
  const int wm = w >> 1, wn = w & 1;
  const int g = blockIdx.x;
  const int a = g & 7, y = (g >> 3) & 7, bidx = g >> 6;
  const int m0 = ((bidx << 1) | (a & 1)) * 128;
  const int n0 = y * 128;
  const int bz = a >> 1;

  f32x4 acc[4][4] = {};
  for (int k0 = 0; k0 < 512; k0 += 64) {
    __syncthreads();
#pragma unroll
    for (int u = 0; u < 2; ++u) {  // A: bf16 row-major gfT, pure b128
      int unit = tid + u * 256;
      int row = unit >> 2, cg = unit & 3;
      const uint4* p = (const uint4*)(gfT + ((size_t)bz * 4096 + m0 + row) * 512 +
                                      k0 + cg * 16);
      *(uint4*)&As[row][cg * 16] = p[0];
      *(uint4*)&As[row][cg * 16 + 8] = p[1];
    }
#pragma unroll
    for (int u = 0; u < 2; ++u) {  // B: Wk or Wv (fp32)
      int unit = tid + u * 256;
      int row = unit >> 2, cg = unit & 3;
      const float* bsrc = (n0 >= 512) ? Wv : Wk;
      size_t nrow = (n0 >= 512) ? (n0 - 512 + row) : (n0 + row);
      ushort_t vals[16];
      rd16f(bsrc + nrow * 512 + k0 + cg * 16, vals);
      *(uint4*)&Bs[row][cg * 16] = *(uint4*)&vals[0];
      *(uint4*)&Bs[row][cg * 16 + 8] = *(uint4*)&vals[8];
    }
    __syncthreads();
#pragma unroll
    for (int kc = 0; kc < 2; ++kc) {
      bf16x8 af[4], bfv[4];
#pragma unroll
      for (int i = 0; i < 4; ++i) {
        af[i] = *(const bf16x8*)&As[wm * 64 + i * 16 + l16][kc * 32 + quad * 8];
        bfv[i] = *(const bf16x8*)&Bs[wn * 64 + i * 16 + l16][kc * 32 + quad * 8];
      }
#pragma unroll
      for (int mt = 0; mt < 4; ++mt)
#pragma unroll
        for (int nt = 0; nt < 4; ++nt)
          acc[mt][nt] = __builtin_amdgcn_mfma_f32_16x16x32_bf16(af[mt], bfv[nt], acc[mt][nt], 0, 0, 0);
    }
  }
  if (n0 < 512) {  // K + RoPE(global)
    const int head = (n0 + wn * 64) >> 6;
#pragma unroll
    for (int mt = 0; mt < 4; ++mt)
#pragma unroll
      for (int r = 0; r < 4; ++r) {
        int pg = m0 + wm * 64 + mt * 16 + quad * 4 + r;
        float x = (float)(pg & 63) * (1.f / 63.f);
        float yy = (float)(pg >> 6) * (1.f / 63.f);
        size_t base = (((size_t)bz * 8 + head) * 4096 + pg) * 64;
#pragma unroll
        for (int j = 0; j < 2; ++j) {
          int c0 = j * 16 + l16;
          float t0 = acc[mt][j][r] + bk[head * 64 + c0];
          float t1 = acc[mt][j + 2][r] + bk[head * 64 + c0 + 32];
          float fr = __expf((float)c0 * (-9.210340371976184f / 32.f));
          float ax = x * fr, ay = yy * fr;
          Kb[base + c0] = __float2bfloat16(t0 * __cosf(ax) - t1 * __sinf(ax));
          Kb[base + c0 + 32] = __float2bfloat16(t1 * __cosf(ay) + t0 * __sinf(ay));
        }
      }
  } else {  // V -> V^T via LDS-bounce
    const int n0v = n0 - 512;
    __syncthreads();
    ushort_t (*T)[136] = (ushort_t(*)[136]) & smem[0][0][0];
#pragma unroll
    for (int mt = 0; mt < 4; ++mt)
#pragma unroll
      for (int nt = 0; nt < 4; ++nt)
#pragma unroll
        for (int r = 0; r < 4; ++r) {
          int n_l = wn * 64 + nt * 16 + l16;
          int m_l = wm * 64 + mt * 16 + quad * 4 + r;
          T[n_l][m_l] = f2bu(acc[mt][nt][r] + bv[n0v + n_l]);
        }
    __syncthreads();
    int row = tid >> 1, half = tid & 1;
    size_t gbase = (((size_t)bz * 8 + (n0v >> 6) + (row >> 6)) * 64 + (row & 63)) * 4096 +
                   m0 + half * 64;
    uint4* dst = (uint4*)(VTb + gbase);
    const uint4* src = (const uint4*)&T[row][half * 64];
#pragma unroll
    for (int j = 0; j < 8; ++j) dst[j] = src[j];
  }
}

// ---------------------------------------------------------------------------
// MFMA flash attention.
// Round-11: the Ps LDS bounce (S-phase -> LDS -> PV-phase) is replaced by an
// in-register quad butterfly: S^T fragment (key=quad*4+r, q=l16) -> PV
// B-fragment (key=quad*8+j, q=l16) via permlane32_swap (bit5) +
// permlane16_swap (bit4), 8 instr/qs. Removes 2 LDS round-trips per chunk
// from the wave's critical path and frees 16KB LDS. K/V are now
// double-buffered in LDS -> ONE barrier per chunk (was 2). Round-10 XOR
// swizzle kept on Ks/VTs. Numerics bit-identical to rounds 9-10.
// ---------------------------------------------------------------------------
template <int NS>
__global__ __launch_bounds__(256, 4) void attn_k(const BF* __restrict__ Q,
                                                 const BF* __restrict__ K,
                                                 const BF* __restrict__ VT,
                                                 BF* __restrict__ AO,
                                                 BF* __restrict__ Opart,
                                                 float* __restrict__ lpart) {
  __shared__ __align__(16) ushort_t Ks[2][64][64];
  __shared__ __align__(16) ushort_t VTs[2][64][64];

  const int tid = threadIdx.x;
  const int w = tid >> 6, lane = tid & 63;
  const int quad = lane >> 4, l16 = lane & 15;
  // Swizzle: element chunk c (16B) of row r lives at chunk c ^ (r & 7).
  // All hot rows are (16k + l16), so row&7 == l16&7 (loop-invariant).
  const int r3 = l16 & 7;
  const int sc0 = (quad ^ r3) << 3;  // swizzled element col of orig chunk `quad`
  const int sc1 = sc0 ^ 32;          // orig chunk quad+4

  const int g = blockIdx.x;
  const int bh = g & 31;               // XCD = bh % 8 (K/V L2-pinned)
  const int qt = (g >> 5) & 7;
  const int ks = g >> 8;
  const int b = bh >> 3, h = bh & 7;
  const int q0 = qt * 128 + w * 32;
  const int kspan = 4096 / NS, kbase = ks * kspan;

  bf16x8 qa[2][2];
#pragma unroll
  for (int qs = 0; qs < 2; ++qs) {
    const BF* qp = Q + (((size_t)bh << 10) + q0 + qs * 16 + l16) * 64 + quad * 8;
    qa[qs][0] = *(const bf16x8*)qp;
    qa[qs][1] = *(const bf16x8*)(qp + 32);
  }
  bf16x8 ones;
#pragma unroll
  for (int j = 0; j < 8; ++j) ones[j] = (__bf16)1.0f;

  const BF* Kp = K + (size_t)bh * 4096 * 64;    // [key][dh]
  const BF* VTp = VT + (size_t)bh * 64 * 4096;  // [dh][key]

  f32x4 o[2][4] = {};
  f32x4 ol[2] = {};

  const int srow = tid >> 2, scol = (tid & 3) * 16;
  const int ssc = ((2 * (tid & 3)) ^ (srow & 7)) << 3;  // swizzled store col
  {  // prologue: stage chunk 0 into buffer 0
    const uint4* kp = (const uint4*)(Kp + (size_t)(kbase + srow) * 64 + scol);
    const uint4* vp = (const uint4*)(VTp + (size_t)srow * 4096 + kbase + scol);
    uint4 a = kp[0], bb = kp[1], c = vp[0], d = vp[1];
    *(uint4*)&Ks[0][srow][ssc] = a;  *(uint4*)&Ks[0][srow][ssc ^ 8] = bb;
    *(uint4*)&VTs[0][srow][ssc] = c; *(uint4*)&VTs[0][srow][ssc ^ 8] = d;
  }
  __syncthreads();

  const int nc = kspan / 64;
  for (int c = 0; c < nc; ++c) {
    const int cur = c & 1;
    uint4 nk0, nk1, nv0, nv1;
    const bool more = (c + 1 < nc);
    if (more) {  // issue next chunk's global loads early (hide under compute)
      const int c1 = kbase + (c + 1) * 64;
      const uint4* kp = (const uint4*)(Kp + (size_t)(c1 + srow) * 64 + scol);
      const uint4* vp = (const uint4*)(VTp + (size_t)srow * 4096 + c1 + scol);
      nk0 = kp[0]; nk1 = kp[1]; nv0 = vp[0]; nv1 = vp[1];
    }

#pragma unroll
    for (int qs = 0; qs < 2; ++qs) {
      // ---- S^T = K Q^T ; P = exp2(S^T), packed bf16 in registers ----
      unsigned Sp[4][2];
#pragma unroll
      for (int ct = 0; ct < 4; ++ct) {
        const int krow = ct * 16 + l16;
        bf16x8 kb0 = *(const bf16x8*)&Ks[cur][krow][sc0];
        bf16x8 kb1 = *(const bf16x8*)&Ks[cur][krow][sc1];
        f32x4 s = {};
        __builtin_amdgcn_s_setprio(1);
        s = __builtin_amdgcn_mfma_f32_16x16x32_bf16(kb0, qa[qs][0], s, 0, 0, 0);
        s = __builtin_amdgcn_mfma_f32_16x16x32_bf16(kb1, qa[qs][1], s, 0, 0, 0);
        __builtin_amdgcn_s_setprio(0);
        Sp[ct][0] = pk2(__builtin_exp2f(s[0]), __builtin_exp2f(s[1]));
        Sp[ct][1] = pk2(__builtin_exp2f(s[2]), __builtin_exp2f(s[3]));
      }
      // ---- quad butterfly: Sp (key=quad*4+r) -> pa (key=quad*8+j) ----
      // Target lane (b5,b4), pa-half hf, slot m: key = hf*32 + (2b5+b4)*8 + 2m.
      // After B5+B4 swaps of (Sp[2hf][h], Sp[2hf+1][h]): a=slot h, b=slot 2+h.
      unsigned pr[8];
#pragma unroll
      for (int hf = 0; hf < 2; ++hf) {
#pragma unroll
        for (int hh = 0; hh < 2; ++hh) {
          unsigned aa = Sp[hf * 2][hh], bb2 = Sp[hf * 2 + 1][hh];
          qswapB5(aa, bb2);
          qswapB4(aa, bb2, lane);
          pr[hf * 4 + hh] = aa;
          pr[hf * 4 + 2 + hh] = bb2;
        }
      }
      uint4v u0 = {pr[0], pr[1], pr[2], pr[3]};
      uint4v u1 = {pr[4], pr[5], pr[6], pr[7]};
      bf16x8 pa0 = __builtin_bit_cast(bf16x8, u0);
      bf16x8 pa1 = __builtin_bit_cast(bf16x8, u1);

      // ---- O^T += V^T P^T ; l += 1^T P^T ----
      __builtin_amdgcn_s_setprio(1);
      ol[qs] = __builtin_amdgcn_mfma_f32_16x16x32_bf16(ones, pa0, ol[qs], 0, 0, 0);
      ol[qs] = __builtin_amdgcn_mfma_f32_16x16x32_bf16(ones, pa1, ol[qs], 0, 0, 0);
#pragma unroll
      for (int nt = 0; nt < 4; ++nt) {
        const int vrow = nt * 16 + l16;
        bf16x8 vb0 = *(const bf16x8*)&VTs[cur][vrow][sc0];
        bf16x8 vb1 = *(const bf16x8*)&VTs[cur][vrow][sc1];
        o[qs][nt] = __builtin_amdgcn_mfma_f32_16x16x32_bf16(vb0, pa0, o[qs][nt], 0, 0, 0);
        o[qs][nt] = __builtin_amdgcn_mfma_f32_16x16x32_bf16(vb1, pa1, o[qs][nt], 0, 0, 0);
      }
      __builtin_amdgcn_s_setprio(0);
    }

    if (more) {  // write next chunk into the other buffer (T14 late-write)
      *(uint4*)&Ks[cur ^ 1][srow][ssc] = nk0;
      *(uint4*)&Ks[cur ^ 1][srow][ssc ^ 8] = nk1;
      *(uint4*)&VTs[cur ^ 1][srow][ssc] = nv0;
      *(uint4*)&VTs[cur ^ 1][srow][ssc ^ 8] = nv1;
    }
    __syncthreads();  // single barrier per chunk (dbuf makes 2nd unnecessary)
  }

  // ---- epilogue: lane holds O^T[dh = nt*16+quad*4+r][q = l16] ----
#pragma unroll
  for (int qs = 0; qs < 2; ++qs) {
    int qg = q0 + qs * 16 + l16;
    if (NS == 1) {
      float invl = 1.f / ol[qs][0];
#pragma unroll
      for (int nt = 0; nt < 4; ++nt) {
        uint2 uu;
        uu.x = pk2(o[qs][nt][0] * invl, o[qs][nt][1] * invl);
        uu.y = pk2(o[qs][nt][2] * invl, o[qs][nt][3] * invl);
        *(uint2*)(AO + (((size_t)b << 10) + qg) * 512 + h * 64 + nt * 16 + quad * 4) = uu;
      }
    } else {
      if (quad == 0) lpart[ks * 32768 + (bh << 10) + qg] = ol[qs][0];
#pragma unroll
      for (int nt = 0; nt < 4; ++nt) {
        uint2 uu;
        uu.x = pk2(o[qs][nt][0], o[qs][nt][1]);
        uu.y = pk2(o[qs][nt][2], o[qs][nt][3]);
        *(uint2*)(Opart + (size_t)ks * 2097152 + (((size_t)bh << 10) + qg) * 64 +
                  nt * 16 + quad * 4) = uu;
      }
    }
  }
}

// ---------------------------------------------------------------------------
// gate_k: gate GEMM (K=1024, A=[local | AO]) + sigmoid-gate epilogue.
// The NS-way K-split merge is FUSED into A-staging (kg>=512 path reads
// Opart/lpart and merges inline) — no reduce_k launch, no AO roundtrip.
// The AO tile needed by the epilogue is captured from LDS at k0==512+n0.
// ---------------------------------------------------------------------------
template <int NS>
__global__ __launch_bounds__(256) void gate_k(const float* __restrict__ local,
                                              const BF* __restrict__ AO,
                                              const BF* __restrict__ Opart,
                                              const float* __restrict__ lpart,
                                              const float* __restrict__ Wg,
                                              const float* __restrict__ bg,
                                              BF* __restrict__ ENH) {
  __shared__ __align__(16) ushort_t As[64][72];
  __shared__ __align__(16) ushort_t Bs[64][72];
  const int tid = threadIdx.x;
  const int w = tid >> 6, lane = tid & 63;
  const int quad = lane >> 4, l16 = lane & 15;
  const int m0 = blockIdx.x * 64, n0 = blockIdx.y * 64;

  f32x4 acc[4] = {};
  float aosv[4][4];  // AO values for epilogue, captured from As
  for (int k0 = 0; k0 < 1024; k0 += 64) {
    __syncthreads();
    {
      int row = tid >> 2, cg = tid & 3;
      int kg = k0 + cg * 16;
      ushort_t vals[16];
      if (kg < 512) {
        rd16f(local + (size_t)(m0 + row) * 512 + kg, vals);
      } else {
        int c = kg - 512;               // 16-aligned, single head per unit
        int hh = c >> 6, dh0 = c & 63;
        int mg = m0 + row;
        size_t bq = (size_t)(((mg >> 10) * 8 + hh) << 10) + (mg & 1023);
        if (NS == 1) {
          const uint4* p = (const uint4*)(AO + (size_t)mg * 512 + c);
          *(uint4*)&vals[0] = p[0]; *(uint4*)&vals[8] = p[1];
        } else {
          float ls = 0.f;
#pragma unroll
          for (int s2 = 0; s2 < NS; ++s2) ls += lpart[s2 * 32768 + bq];
          float inv = 1.f / ls;
          float av[16] = {};
#pragma unroll
          for (int s2 = 0; s2 < NS; ++s2) {
            const ushort_t* op = (const ushort_t*)Opart + (size_t)s2 * 2097152 +
                                 bq * 64 + dh0;
            uint4 u0 = ((const uint4*)op)[0], u1 = ((const uint4*)op)[1];
            const ushort_t* pu = (const ushort_t*)&u0;
#pragma unroll
            for (int j = 0; j < 8; ++j) av[j] += bu2f(pu[j]);
            pu = (const ushort_t*)&u1;
#pragma unroll
            for (int j = 0; j < 8; ++j) av[8 + j] += bu2f(pu[j]);
          }
#pragma unroll
          for (int j = 0; j < 16; j += 2)
            ((unsigned*)vals)[j / 2] = pk2(av[j] * inv, av[j + 1] * inv);
        }
      }
      *(uint4*)&As[row][cg * 16] = *(uint4*)&vals[0];
      *(uint4*)&As[row][cg * 16 + 8] = *(uint4*)&vals[8];
      ushort_t bv[16];
      rd16f(Wg + (size_t)(n0 + row) * 1024 + kg, bv);
      *(uint4*)&Bs[row][cg * 16] = *(uint4*)&bv[0];
      *(uint4*)&Bs[row][cg * 16 + 8] = *(uint4*)&bv[8];
    }
    __syncthreads();
    if (k0 == 512 + n0) {  // capture this block's AO tile for the epilogue
#pragma unroll
      for (int r = 0; r < 4; ++r)
#pragma unroll
        for (int nt = 0; nt < 4; ++nt)
          aosv[r][nt] = bu2f(As[w * 16 + quad * 4 + r][nt * 16 + l16]);
    }
#pragma unroll
    for (int kc = 0; kc < 2; ++kc) {
      bf16x8 af = *(const bf16x8*)&As[w * 16 + l16][kc * 32 + quad * 8];
#pragma unroll
      for (int nt = 0; nt < 4; ++nt) {
        bf16x8 bfv = *(const bf16x8*)&Bs[nt * 16 + l16][kc * 32 + quad * 8];
        acc[nt] = __builtin_amdgcn_mfma_f32_16x16x32_bf16(af, bfv, acc[nt], 0, 0, 0);
      }
    }
  }
#pragma unroll
  for (int r = 0; r < 4; ++r) {
    int mg = m0 + w * 16 + quad * 4 + r;
#pragma unroll
    for (int nt = 0; nt < 4; ++nt) {
      int ng = n0 + nt * 16 + l16;
      size_t idx = (size_t)mg * 512 + ng;
      float gg = 1.f / (1.f + __expf(-(acc[nt][r] + bg[ng])));
      ENH[idx] = __float2bfloat16(local[idx] + gg * aosv[r][nt]);
    }
  }
}

// ---------------------------------------------------------------------------
// out_k: final projection, fp32 output.
// ---------------------------------------------------------------------------
__global__ __launch_bounds__(256) void out_k(const BF* __restrict__ ENH,
                                             const float* __restrict__ Wo,
                                             const float* __restrict__ bo,
                                             float* __restrict__ out) {
  __shared__ __align__(16) ushort_t As[64][72];
  __shared__ __align__(16) ushort_t Bs[64][72];
  const int tid = threadIdx.x;
  const int w = tid >> 6, lane = tid & 63;
  const int quad = lane >> 4, l16 = lane & 15;
  const int m0 = blockIdx.x * 64, n0 = blockIdx.y * 64;

  f32x4 acc[4] = {};
  for (int k0 = 0; k0 < 512; k0 += 64) {
    __syncthreads();
    {
      int row = tid >> 2, cg = tid & 3;
      int kg = k0 + cg * 16;
      const uint4* p = (const uint4*)(ENH + (size_t)(m0 + row) * 512 + kg);
      *(uint4*)&As[row][cg * 16] = p[0];
      *(uint4*)&As[row][cg * 16 + 8] = p[1];
      ushort_t bv[16];
      rd16f(Wo + (size_t)(n0 + row) * 512 + kg, bv);
      *(uint4*)&Bs[row][cg * 16] = *(uint4*)&bv[0];
      *(uint4*)&Bs[row][cg * 16 + 8] = *(uint4*)&bv[8];
    }
    __syncthreads();
#pragma unroll
    for (int kc = 0; kc < 2; ++kc) {
      bf16x8 af = *(const bf16x8*)&As[w * 16 + l16][kc * 32 + quad * 8];
#pragma unroll
      for (int nt = 0; nt < 4; ++nt) {
        bf16x8 bfv = *(const bf16x8*)&Bs[nt * 16 + l16][kc * 32 + quad * 8];
        acc[nt] = __builtin_amdgcn_mfma_f32_16x16x32_bf16(af, bfv, acc[nt], 0, 0, 0);
      }
    }
  }
#pragma unroll
  for (int r = 0; r < 4; ++r) {
    int mg = m0 + w * 16 + quad * 4 + r;
#pragma unroll
    for (int nt = 0; nt < 4; ++nt) {
      int ng = n0 + nt * 16 + l16;
      out[(size_t)mg * 512 + ng] = acc[nt][r] + bo[ng];
    }
  }
}

extern "C" void kernel_launch(void* const* d_in, const int* in_sizes, int n_in,
                              void* d_out, int out_size, void* d_ws, size_t ws_size,
                              hipStream_t stream) {
  const float* local = (const float*)d_in[0];
  const float* gfeat = (const float*)d_in[1];
  const float* Wq = (const float*)d_in[2];
  const float* bq = (const float*)d_in[3];
  const float* Wk = (const float*)d_in[4];
  const float* bk = (const float*)d_in[5];
  const float* Wv = (const float*)d_in[6];
  const float* bv = (const float*)d_in[7];
  const float* Wg = (const float*)d_in[8];
  const float* bg = (const float*)d_in[9];
  const float* Wo = (const float*)d_in[10];
  const float* bo = (const float*)d_in[11];

  char* w = (char*)d_ws;
  BF* Qb = (BF*)w;            w += (size_t)2097152 * 2;  // 4 MB (reused as ENH)
  BF* Kb = (BF*)w;            w += (size_t)8388608 * 2;  // 16 MB
  BF* VTb = (BF*)w;           w += (size_t)8388608 * 2;  // 16 MB (V^T [b,h,dh,key])
  BF* AO = (BF*)w;            w += (size_t)2097152 * 2;  // 4 MB (NS==1 only)
  // Region X: gfT (16 MB, dead after kv_k) aliases Opart (NS x 4 MB).
  BF* gfT = (BF*)w;
  BF* Opart = (BF*)w;
  size_t baseOff = (size_t)(w - (char*)d_ws);
  BF* ENH = Qb;

  int NS = 1;
  if (baseOff + 4 * (4194304 + 131072) <= ws_size) NS = 4;
  else if (baseOff + 16777216 + 2 * 131072 <= ws_size) NS = 2;
  float* lpart = (float*)(w + (size_t)NS * 4194304);

  dim3 blk(256);
  pre_k<<<dim3(2560), blk, 0, stream>>>(local, gfeat, Wq, bq, gfT, Qb);
  kv_k<<<dim3(1024), blk, 0, stream>>>(gfT, Wk, Wv, bk, bv, Kb, VTb);
  if (NS == 4) {
    attn_k<4><<<dim3(1024), blk, 0, stream>>>(Qb, Kb, VTb, AO, Opart, lpart);
    gate_k<4><<<dim3(64, 8), blk, 0, stream>>>(local, AO, Opart, lpart, Wg, bg, ENH);
  } else if (NS == 2) {
    attn_k<2><<<dim3(512), blk, 0, stream>>>(Qb, Kb, VTb, AO, Opart, lpart);
    gate_k<2><<<dim3(64, 8), blk, 0, stream>>>(local, AO, Opart, lpart, Wg, bg, ENH);
  } else {
    attn_k<1><<<dim3(256), blk, 0, stream>>>(Qb, Kb, VTb, AO, nullptr, nullptr);
    gate_k<1><<<dim3(64, 8), blk, 0, stream>>>(local, AO, Opart, lpart, Wg, bg, ENH);
  }
  out_k<<<dim3(64, 8), blk, 0, stream>>>(ENH, Wo, bo, (float*)d_out);
}

// Round 3
// 248.164 us; speedup vs baseline: 1.0702x; 1.0056x over previous
//
#include <hip/hip_runtime.h>
#include <hip/hip_bf16.h>
#include <cstdint>

typedef __hip_bfloat16 BF;
typedef unsigned short ushort_t;
typedef __attribute__((ext_vector_type(8))) __bf16 bf16x8;
typedef __attribute__((ext_vector_type(4))) float f32x4;
typedef __attribute__((ext_vector_type(4))) unsigned uint4v;

// Inputs/outputs are fp32 (established empirically rounds 2-9: detect flag
// always f32; fp32 output stores passed). Internal tensors bf16.
__device__ __forceinline__ float bu2f(ushort_t u) {
  return __uint_as_float((unsigned)u << 16);
}
__device__ __forceinline__ unsigned pk2(float a, float b) {
  union { __hip_bfloat162 h; unsigned u; } c;
  c.h = __float22bfloat162_rn(make_float2(a, b));  // v_cvt_pk_bf16_f32
  return c.u;
}
__device__ __forceinline__ unsigned short f2bu(float f) {
  union { BF b; unsigned short u; } c; c.b = __float2bfloat16(f); return c.u;
}
__device__ __forceinline__ float b2f(BF x) { return __bfloat162float(x); }
// 16 fp32 -> 16 bf16 bit patterns (8 packed converts).
__device__ __forceinline__ void rd16f(const float* fp, ushort_t* out) {
#pragma unroll
  for (int j = 0; j < 16; j += 4) {
    float4 v = *(const float4*)(fp + j);
    ((unsigned*)out)[j / 2] = pk2(v.x, v.y);
    ((unsigned*)out)[j / 2 + 1] = pk2(v.z, v.w);
  }
}

#define QS 0.1803368801111f  // (1/8)*log2(e): folded into Q so attn uses exp2

// ---------------------------------------------------------------------------
// pre_k: fused [gfeat transpose+cvt] + [Q projection w/ RoPE].
// blocks [0,2048): gfT[bz][m][k] bf16 <- gfeat[bz][k][m] fp32.
// blocks [2048,2560): Q = RoPE(local @ Wq^T + bq) * QS, 64x64 tiles.
// ---------------------------------------------------------------------------
__global__ __launch_bounds__(256) void pre_k(const float* __restrict__ local,
                                             const float* __restrict__ gfeat,
                                             const float* __restrict__ Wq,
                                             const float* __restrict__ bq,
                                             BF* __restrict__ gfT,
                                             BF* __restrict__ Qb) {
  __shared__ __align__(16) ushort_t smem[2][64][72];
  const int t = threadIdx.x;
  if (blockIdx.x < 2048) {
    auto T = smem[0];
    const int g = blockIdx.x;  // 4 bz x 64 mt x 8 kt
    const int bz = g & 3, mt = (g >> 2) & 63, kt = g >> 8;
    {
      int krow = t >> 2, mg = t & 3;
      ushort_t vals[16];
      rd16f(gfeat + (size_t)bz * 512 * 4096 + (size_t)(kt * 64 + krow) * 4096 +
                mt * 64 + mg * 16,
            vals);
#pragma unroll
      for (int j = 0; j < 16; ++j) T[mg * 16 + j][krow] = vals[j];
    }
    __syncthreads();
    int mrow = t >> 2, kg = t & 3;
    uint4 a = *(const uint4*)&T[mrow][kg * 16];
    uint4 b = *(const uint4*)&T[mrow][kg * 16 + 8];
    size_t o = ((size_t)bz * 4096 + mt * 64 + mrow) * 512 + kt * 64 + kg * 16;
    *(uint4*)&gfT[o] = a;
    *(uint4*)&gfT[o + 8] = b;
    return;
  }
  // ---- Q projection ----
  auto As = smem[0];
  auto Bs = smem[1];
  const int bx = blockIdx.x - 2048;
  const int m0 = (bx & 63) * 64, n0 = (bx >> 6) * 64;
  const int w = t >> 6, lane = t & 63;
  const int quad = lane >> 4, l16 = lane & 15;

  f32x4 acc[4] = {};
  for (int k0 = 0; k0 < 512; k0 += 64) {
    __syncthreads();
    {
      int row = t >> 2, cg = t & 3;
      int kg = k0 + cg * 16;
      ushort_t vals[16];
      rd16f(local + (size_t)(m0 + row) * 512 + kg, vals);
      *(uint4*)&As[row][cg * 16] = *(uint4*)&vals[0];
      *(uint4*)&As[row][cg * 16 + 8] = *(uint4*)&vals[8];
      ushort_t bv[16];
      rd16f(Wq + (size_t)(n0 + row) * 512 + kg, bv);
      *(uint4*)&Bs[row][cg * 16] = *(uint4*)&bv[0];
      *(uint4*)&Bs[row][cg * 16 + 8] = *(uint4*)&bv[8];
    }
    __syncthreads();
#pragma unroll
    for (int kc = 0; kc < 2; ++kc) {
      bf16x8 af = *(const bf16x8*)&As[w * 16 + l16][kc * 32 + quad * 8];
#pragma unroll
      for (int nt = 0; nt < 4; ++nt) {
        bf16x8 bfv = *(const bf16x8*)&Bs[nt * 16 + l16][kc * 32 + quad * 8];
        acc[nt] = __builtin_amdgcn_mfma_f32_16x16x32_bf16(af, bfv, acc[nt], 0, 0, 0);
      }
    }
  }
  const int head = n0 >> 6;
#pragma unroll
  for (int r = 0; r < 4; ++r) {
    int mg = m0 + w * 16 + quad * 4 + r;
    int bb = mg >> 10, qi = mg & 1023;
    float x = (float)(qi & 31) * (1.f / 31.f);
    float y = (float)(qi >> 5) * (1.f / 31.f);
    size_t base = (((size_t)bb * 8 + head) * 1024 + qi) * 64;
#pragma unroll
    for (int j = 0; j < 2; ++j) {
      int c0 = j * 16 + l16;
      float t0 = acc[j][r] + bq[head * 64 + c0];
      float t1 = acc[j + 2][r] + bq[head * 64 + c0 + 32];
      float fr = __expf((float)c0 * (-9.210340371976184f / 32.f));
      float ax = x * fr, ay = y * fr;
      Qb[base + c0] = __float2bfloat16((t0 * __cosf(ax) - t1 * __sinf(ax)) * QS);
      Qb[base + c0 + 32] = __float2bfloat16((t1 * __cosf(ay) + t0 * __sinf(ay)) * QS);
    }
  }
}

// ---------------------------------------------------------------------------
// kv_k: fused K/V projection from pre-transposed bf16 gfT. 128x128 tile,
// 1D XCD-pinned grid. n0<512 -> K+RoPE(global); else V -> V^T via LDS bounce.
// ---------------------------------------------------------------------------
__global__ __launch_bounds__(256) void kv_k(const BF* __restrict__ gfT,
                                            const float* __restrict__ Wk,
                                            const float* __restrict__ Wv,
                                            const float* __restrict__ bk,
                                            const float* __restrict__ bv,
                                            BF* __restrict__ Kb,
                                            BF* __restrict__ VTb) {
  __shared__ __align__(16) ushort_t smem[2][128][72];
  auto As = smem[0];
  auto Bs = smem[1];
  const int tid = threadIdx.x;
  const int w = tid >> 6, lane = tid & 63;
  const int quad = lane >> 4, l16 = lane & 15;
  const int wm = w >> 1, wn = w & 1;
  const int g = blockIdx.x;
  const int a = g & 7, y = (g >> 3) & 7, bidx = g >> 6;
  const int m0 = ((bidx << 1) | (a & 1)) * 128;
  const int n0 = y * 128;
  const int bz = a >> 1;

  f32x4 acc[4][4] = {};
  for (int k0 = 0; k0 < 512; k0 += 64) {
    __syncthreads();
#pragma unroll
    for (int u = 0; u < 2; ++u) {  // A: bf16 row-major gfT, pure b128
      int unit = tid + u * 256;
      int row = unit >> 2, cg = unit & 3;
      const uint4* p = (const uint4*)(gfT + ((size_t)bz * 4096 + m0 + row) * 512 +
                                      k0 + cg * 16);
      *(uint4*)&As[row][cg * 16] = p[0];
      *(uint4*)&As[row][cg * 16 + 8] = p[1];
    }
#pragma unroll
    for (int u = 0; u < 2; ++u) {  // B: Wk or Wv (fp32)
      int unit = tid + u * 256;
      int row = unit >> 2, cg = unit & 3;
      const float* bsrc = (n0 >= 512) ? Wv : Wk;
      size_t nrow = (n0 >= 512) ? (n0 - 512 + row) : (n0 + row);
      ushort_t vals[16];
      rd16f(bsrc + nrow * 512 + k0 + cg * 16, vals);
      *(uint4*)&Bs[row][cg * 16] = *(uint4*)&vals[0];
      *(uint4*)&Bs[row][cg * 16 + 8] = *(uint4*)&vals[8];
    }
    __syncthreads();
#pragma unroll
    for (int kc = 0; kc < 2; ++kc) {
      bf16x8 af[4], bfv[4];
#pragma unroll
      for (int i = 0; i < 4; ++i) {
        af[i] = *(const bf16x8*)&As[wm * 64 + i * 16 + l16][kc * 32 + quad * 8];
        bfv[i] = *(const bf16x8*)&Bs[wn * 64 + i * 16 + l16][kc * 32 + quad * 8];
      }
#pragma unroll
      for (int mt = 0; mt < 4; ++mt)
#pragma unroll
        for (int nt = 0; nt < 4; ++nt)
          acc[mt][nt] = __builtin_amdgcn_mfma_f32_16x16x32_bf16(af[mt], bfv[nt], acc[mt][nt], 0, 0, 0);
    }
  }
  if (n0 < 512) {  // K + RoPE(global)
    const int head = (n0 + wn * 64) >> 6;
#pragma unroll
    for (int mt = 0; mt < 4; ++mt)
#pragma unroll
      for (int r = 0; r < 4; ++r) {
        int pg = m0 + wm * 64 + mt * 16 + quad * 4 + r;
        float x = (float)(pg & 63) * (1.f / 63.f);
        float yy = (float)(pg >> 6) * (1.f / 63.f);
        size_t base = (((size_t)bz * 8 + head) * 4096 + pg) * 64;
#pragma unroll
        for (int j = 0; j < 2; ++j) {
          int c0 = j * 16 + l16;
          float t0 = acc[mt][j][r] + bk[head * 64 + c0];
          float t1 = acc[mt][j + 2][r] + bk[head * 64 + c0 + 32];
          float fr = __expf((float)c0 * (-9.210340371976184f / 32.f));
          float ax = x * fr, ay = yy * fr;
          Kb[base + c0] = __float2bfloat16(t0 * __cosf(ax) - t1 * __sinf(ax));
          Kb[base + c0 + 32] = __float2bfloat16(t1 * __cosf(ay) + t0 * __sinf(ay));
        }
      }
  } else {  // V -> V^T via LDS-bounce
    const int n0v = n0 - 512;
    __syncthreads();
    ushort_t (*T)[136] = (ushort_t(*)[136]) & smem[0][0][0];
#pragma unroll
    for (int mt = 0; mt < 4; ++mt)
#pragma unroll
      for (int nt = 0; nt < 4; ++nt)
#pragma unroll
        for (int r = 0; r < 4; ++r) {
          int n_l = wn * 64 + nt * 16 + l16;
          int m_l = wm * 64 + mt * 16 + quad * 4 + r;
          T[n_l][m_l] = f2bu(acc[mt][nt][r] + bv[n0v + n_l]);
        }
    __syncthreads();
    int row = tid >> 1, half = tid & 1;
    size_t gbase = (((size_t)bz * 8 + (n0v >> 6) + (row >> 6)) * 64 + (row & 63)) * 4096 +
                   m0 + half * 64;
    uint4* dst = (uint4*)(VTb + gbase);
    const uint4* src = (const uint4*)&T[row][half * 64];
#pragma unroll
    for (int j = 0; j < 8; ++j) dst[j] = src[j];
  }
}

// ---------------------------------------------------------------------------
// MFMA flash attention.
// Round-12: LDS-pipe relief. (a) ct-outer/nt-outer loops: each K/V b128 LDS
// read now feeds BOTH qs MFMA pairs -> 16 b128 reads/chunk (was 32) — the
// structural floor for this fragment tiling. (b) the round-11 permlane
// butterfly is deleted: V is staged with a key-bit-permutation
// pi(p5..p0)=(p5,p2,p4,p3,p1,p0) on the VTs column axis, chosen so the
// S-output fragment (key=ct*16+quad*4+r) IS the PV B-fragment
// (slot ks*32+quad*8+j, ks=ct>>1, j=(ct&1)*4+r) with zero cross-lane moves
// (sum over keys is order-invariant; P and V use the same permutation).
// V staging becomes 4x b64 scatter (same LDS-write cost, conflict-free).
// Double-buffered K/V, one barrier/chunk, register prefetch, exp2 softmax
// (scale folded into Q), XOR bank swizzle on rows. MFMA K-reduction order
// changes within 32-key groups -> sub-ULP reassociation only.
// ---------------------------------------------------------------------------
template <int NS>
__global__ __launch_bounds__(256, 4) void attn_k(const BF* __restrict__ Q,
                                                 const BF* __restrict__ K,
                                                 const BF* __restrict__ VT,
                                                 BF* __restrict__ AO,
                                                 BF* __restrict__ Opart,
                                                 float* __restrict__ lpart) {
  __shared__ __align__(16) ushort_t Ks[2][64][64];
  __shared__ __align__(16) ushort_t VTs[2][64][64];

  const int tid = threadIdx.x;
  const int w = tid >> 6, lane = tid & 63;
  const int quad = lane >> 4, l16 = lane & 15;
  // Swizzle: element chunk c (16B) of row r lives at chunk c ^ (r & 7).
  // All hot rows are (16k + l16), so row&7 == l16&7 (loop-invariant).
  const int r3 = l16 & 7;
  const int sc0 = (quad ^ r3) << 3;  // swizzled element col of orig chunk `quad`
  const int sc1 = sc0 ^ 32;          // orig chunk quad+4

  const int g = blockIdx.x;
  const int bh = g & 31;               // XCD = bh % 8 (K/V L2-pinned)
  const int qt = (g >> 5) & 7;
  const int ks = g >> 8;
  const int b = bh >> 3, h = bh & 7;
  const int q0 = qt * 128 + w * 32;
  const int kspan = 4096 / NS, kbase = ks * kspan;

  bf16x8 qa[2][2];
#pragma unroll
  for (int qs = 0; qs < 2; ++qs) {
    const BF* qp = Q + (((size_t)bh << 10) + q0 + qs * 16 + l16) * 64 + quad * 8;
    qa[qs][0] = *(const bf16x8*)qp;
    qa[qs][1] = *(const bf16x8*)(qp + 32);
  }
  bf16x8 ones;
#pragma unroll
  for (int j = 0; j < 8; ++j) ones[j] = (__bf16)1.0f;

  const BF* Kp = K + (size_t)bh * 4096 * 64;    // [key][dh]
  const BF* VTp = VT + (size_t)bh * 64 * 4096;  // [dh][key]

  f32x4 o[2][4] = {};
  f32x4 ol[2] = {};

  const int srow = tid >> 2, scol = (tid & 3) * 16;
  const int ssc = ((2 * (tid & 3)) ^ (srow & 7)) << 3;  // K swizzled store col
  // V store columns: global key g (16 per thread) lands at logical position
  // p = s1*32 + t3*16 + t2*8 + s0*4 + (t&3)  (s1s0 = tid&3, t = g&15),
  // i.e. 4 b64 groups; physical col applies the 16B-chunk XOR swizzle.
  int vcol[4];
  {
    const int s1 = (tid >> 1) & 1, s0v = tid & 1;
#pragma unroll
    for (int gq = 0; gq < 4; ++gq)
      vcol[gq] = (((s1 * 4 + gq) ^ (srow & 7)) << 3) + s0v * 4;
  }

#define STAGE_V(buf, v0, v1)                                   \
  {                                                            \
    uint2 t_;                                                  \
    t_.x = (v0).x; t_.y = (v0).y; *(uint2*)&VTs[buf][srow][vcol[0]] = t_; \
    t_.x = (v0).z; t_.y = (v0).w; *(uint2*)&VTs[buf][srow][vcol[1]] = t_; \
    t_.x = (v1).x; t_.y = (v1).y; *(uint2*)&VTs[buf][srow][vcol[2]] = t_; \
    t_.x = (v1).z; t_.y = (v1).w; *(uint2*)&VTs[buf][srow][vcol[3]] = t_; \
  }

  {  // prologue: stage chunk 0 into buffer 0
    const uint4* kp = (const uint4*)(Kp + (size_t)(kbase + srow) * 64 + scol);
    const uint4* vp = (const uint4*)(VTp + (size_t)srow * 4096 + kbase + scol);
    uint4 a = kp[0], bb = kp[1], c = vp[0], d = vp[1];
    *(uint4*)&Ks[0][srow][ssc] = a;  *(uint4*)&Ks[0][srow][ssc ^ 8] = bb;
    STAGE_V(0, c, d);
  }
  __syncthreads();

  const int nc = kspan / 64;
  for (int c = 0; c < nc; ++c) {
    const int cur = c & 1;
    uint4 nk0, nk1, nv0, nv1;
    const bool more = (c + 1 < nc);
    if (more) {  // issue next chunk's global loads early (hide under compute)
      const int c1 = kbase + (c + 1) * 64;
      const uint4* kp = (const uint4*)(Kp + (size_t)(c1 + srow) * 64 + scol);
      const uint4* vp = (const uint4*)(VTp + (size_t)srow * 4096 + c1 + scol);
      nk0 = kp[0]; nk1 = kp[1]; nv0 = vp[0]; nv1 = vp[1];
    }

    // ---- S^T = K Q^T ; P = exp2(S^T) packed straight into PV B-fragments ----
    unsigned pa_u[2][2][4];  // [qs][ks32][word]
#pragma unroll
    for (int ct = 0; ct < 4; ++ct) {
      const int krow = ct * 16 + l16;
      bf16x8 kb0 = *(const bf16x8*)&Ks[cur][krow][sc0];
      bf16x8 kb1 = *(const bf16x8*)&Ks[cur][krow][sc1];
#pragma unroll
      for (int qs = 0; qs < 2; ++qs) {
        f32x4 s = {};
        __builtin_amdgcn_s_setprio(1);
        s = __builtin_amdgcn_mfma_f32_16x16x32_bf16(kb0, qa[qs][0], s, 0, 0, 0);
        s = __builtin_amdgcn_mfma_f32_16x16x32_bf16(kb1, qa[qs][1], s, 0, 0, 0);
        __builtin_amdgcn_s_setprio(0);
        pa_u[qs][ct >> 1][(ct & 1) * 2] =
            pk2(__builtin_exp2f(s[0]), __builtin_exp2f(s[1]));
        pa_u[qs][ct >> 1][(ct & 1) * 2 + 1] =
            pk2(__builtin_exp2f(s[2]), __builtin_exp2f(s[3]));
      }
    }
    bf16x8 pa[2][2];
#pragma unroll
    for (int qs = 0; qs < 2; ++qs)
#pragma unroll
      for (int kk = 0; kk < 2; ++kk) {
        uint4v u = {pa_u[qs][kk][0], pa_u[qs][kk][1], pa_u[qs][kk][2],
                    pa_u[qs][kk][3]};
        pa[qs][kk] = __builtin_bit_cast(bf16x8, u);
      }

    // ---- O^T += V^T P^T ; l += 1^T P^T (each vb read feeds both qs) ----
    __builtin_amdgcn_s_setprio(1);
#pragma unroll
    for (int qs = 0; qs < 2; ++qs) {
      ol[qs] = __builtin_amdgcn_mfma_f32_16x16x32_bf16(ones, pa[qs][0], ol[qs], 0, 0, 0);
      ol[qs] = __builtin_amdgcn_mfma_f32_16x16x32_bf16(ones, pa[qs][1], ol[qs], 0, 0, 0);
    }
#pragma unroll
    for (int nt = 0; nt < 4; ++nt) {
      const int vrow = nt * 16 + l16;
      bf16x8 vb0 = *(const bf16x8*)&VTs[cur][vrow][sc0];
      bf16x8 vb1 = *(const bf16x8*)&VTs[cur][vrow][sc1];
#pragma unroll
      for (int qs = 0; qs < 2; ++qs) {
        o[qs][nt] = __builtin_amdgcn_mfma_f32_16x16x32_bf16(vb0, pa[qs][0], o[qs][nt], 0, 0, 0);
        o[qs][nt] = __builtin_amdgcn_mfma_f32_16x16x32_bf16(vb1, pa[qs][1], o[qs][nt], 0, 0, 0);
      }
    }
    __builtin_amdgcn_s_setprio(0);

    if (more) {  // write next chunk into the other buffer (T14 late-write)
      *(uint4*)&Ks[cur ^ 1][srow][ssc] = nk0;
      *(uint4*)&Ks[cur ^ 1][srow][ssc ^ 8] = nk1;
      STAGE_V(cur ^ 1, nv0, nv1);
    }
    __syncthreads();  // single barrier per chunk (dbuf makes 2nd unnecessary)
  }
#undef STAGE_V

  // ---- epilogue: lane holds O^T[dh = nt*16+quad*4+r][q = l16] ----
#pragma unroll
  for (int qs = 0; qs < 2; ++qs) {
    int qg = q0 + qs * 16 + l16;
    if (NS == 1) {
      float invl = 1.f / ol[qs][0];
#pragma unroll
      for (int nt = 0; nt < 4; ++nt) {
        uint2 uu;
        uu.x = pk2(o[qs][nt][0] * invl, o[qs][nt][1] * invl);
        uu.y = pk2(o[qs][nt][2] * invl, o[qs][nt][3] * invl);
        *(uint2*)(AO + (((size_t)b << 10) + qg) * 512 + h * 64 + nt * 16 + quad * 4) = uu;
      }
    } else {
      if (quad == 0) lpart[ks * 32768 + (bh << 10) + qg] = ol[qs][0];
#pragma unroll
      for (int nt = 0; nt < 4; ++nt) {
        uint2 uu;
        uu.x = pk2(o[qs][nt][0], o[qs][nt][1]);
        uu.y = pk2(o[qs][nt][2], o[qs][nt][3]);
        *(uint2*)(Opart + (size_t)ks * 2097152 + (((size_t)bh << 10) + qg) * 64 +
                  nt * 16 + quad * 4) = uu;
      }
    }
  }
}

// ---------------------------------------------------------------------------
// gate_k: gate GEMM (K=1024, A=[local | AO]) + sigmoid-gate epilogue.
// The NS-way K-split merge is FUSED into A-staging (kg>=512 path reads
// Opart/lpart and merges inline) — no reduce_k launch, no AO roundtrip.
// The AO tile needed by the epilogue is captured from LDS at k0==512+n0.
// ---------------------------------------------------------------------------
template <int NS>
__global__ __launch_bounds__(256) void gate_k(const float* __restrict__ local,
                                              const BF* __restrict__ AO,
                                              const BF* __restrict__ Opart,
                                              const float* __restrict__ lpart,
                                              const float* __restrict__ Wg,
                                              const float* __restrict__ bg,
                                              BF* __restrict__ ENH) {
  __shared__ __align__(16) ushort_t As[64][72];
  __shared__ __align__(16) ushort_t Bs[64][72];
  const int tid = threadIdx.x;
  const int w = tid >> 6, lane = tid & 63;
  const int quad = lane >> 4, l16 = lane & 15;
  const int m0 = blockIdx.x * 64, n0 = blockIdx.y * 64;

  f32x4 acc[4] = {};
  float aosv[4][4];  // AO values for epilogue, captured from As
  for (int k0 = 0; k0 < 1024; k0 += 64) {
    __syncthreads();
    {
      int row = tid >> 2, cg = tid & 3;
      int kg = k0 + cg * 16;
      ushort_t vals[16];
      if (kg < 512) {
        rd16f(local + (size_t)(m0 + row) * 512 + kg, vals);
      } else {
        int c = kg - 512;               // 16-aligned, single head per unit
        int hh = c >> 6, dh0 = c & 63;
        int mg = m0 + row;
        size_t bq = (size_t)(((mg >> 10) * 8 + hh) << 10) + (mg & 1023);
        if (NS == 1) {
          const uint4* p = (const uint4*)(AO + (size_t)mg * 512 + c);
          *(uint4*)&vals[0] = p[0]; *(uint4*)&vals[8] = p[1];
        } else {
          float ls = 0.f;
#pragma unroll
          for (int s2 = 0; s2 < NS; ++s2) ls += lpart[s2 * 32768 + bq];
          float inv = 1.f / ls;
          float av[16] = {};
#pragma unroll
          for (int s2 = 0; s2 < NS; ++s2) {
            const ushort_t* op = (const ushort_t*)Opart + (size_t)s2 * 2097152 +
                                 bq * 64 + dh0;
            uint4 u0 = ((const uint4*)op)[0], u1 = ((const uint4*)op)[1];
            const ushort_t* pu = (const ushort_t*)&u0;
#pragma unroll
            for (int j = 0; j < 8; ++j) av[j] += bu2f(pu[j]);
            pu = (const ushort_t*)&u1;
#pragma unroll
            for (int j = 0; j < 8; ++j) av[8 + j] += bu2f(pu[j]);
          }
#pragma unroll
          for (int j = 0; j < 16; j += 2)
            ((unsigned*)vals)[j / 2] = pk2(av[j] * inv, av[j + 1] * inv);
        }
      }
      *(uint4*)&As[row][cg * 16] = *(uint4*)&vals[0];
      *(uint4*)&As[row][cg * 16 + 8] = *(uint4*)&vals[8];
      ushort_t bv[16];
      rd16f(Wg + (size_t)(n0 + row) * 1024 + kg, bv);
      *(uint4*)&Bs[row][cg * 16] = *(uint4*)&bv[0];
      *(uint4*)&Bs[row][cg * 16 + 8] = *(uint4*)&bv[8];
    }
    __syncthreads();
    if (k0 == 512 + n0) {  // capture this block's AO tile for the epilogue
#pragma unroll
      for (int r = 0; r < 4; ++r)
#pragma unroll
        for (int nt = 0; nt < 4; ++nt)
          aosv[r][nt] = bu2f(As[w * 16 + quad * 4 + r][nt * 16 + l16]);
    }
#pragma unroll
    for (int kc = 0; kc < 2; ++kc) {
      bf16x8 af = *(const bf16x8*)&As[w * 16 + l16][kc * 32 + quad * 8];
#pragma unroll
      for (int nt = 0; nt < 4; ++nt) {
        bf16x8 bfv = *(const bf16x8*)&Bs[nt * 16 + l16][kc * 32 + quad * 8];
        acc[nt] = __builtin_amdgcn_mfma_f32_16x16x32_bf16(af, bfv, acc[nt], 0, 0, 0);
      }
    }
  }
#pragma unroll
  for (int r = 0; r < 4; ++r) {
    int mg = m0 + w * 16 + quad * 4 + r;
#pragma unroll
    for (int nt = 0; nt < 4; ++nt) {
      int ng = n0 + nt * 16 + l16;
      size_t idx = (size_t)mg * 512 + ng;
      float gg = 1.f / (1.f + __expf(-(acc[nt][r] + bg[ng])));
      ENH[idx] = __float2bfloat16(local[idx] + gg * aosv[r][nt]);
    }
  }
}

// ---------------------------------------------------------------------------
// out_k: final projection, fp32 output.
// ---------------------------------------------------------------------------
__global__ __launch_bounds__(256) void out_k(const BF* __restrict__ ENH,
                                             const float* __restrict__ Wo,
                                             const float* __restrict__ bo,
                                             float* __restrict__ out) {
  __shared__ __align__(16) ushort_t As[64][72];
  __shared__ __align__(16) ushort_t Bs[64][72];
  const int tid = threadIdx.x;
  const int w = tid >> 6, lane = tid & 63;
  const int quad = lane >> 4, l16 = lane & 15;
  const int m0 = blockIdx.x * 64, n0 = blockIdx.y * 64;

  f32x4 acc[4] = {};
  for (int k0 = 0; k0 < 512; k0 += 64) {
    __syncthreads();
    {
      int row = tid >> 2, cg = tid & 3;
      int kg = k0 + cg * 16;
      const uint4* p = (const uint4*)(ENH + (size_t)(m0 + row) * 512 + kg);
      *(uint4*)&As[row][cg * 16] = p[0];
      *(uint4*)&As[row][cg * 16 + 8] = p[1];
      ushort_t bv[16];
      rd16f(Wo + (size_t)(n0 + row) * 512 + kg, bv);
      *(uint4*)&Bs[row][cg * 16] = *(uint4*)&bv[0];
      *(uint4*)&Bs[row][cg * 16 + 8] = *(uint4*)&bv[8];
    }
    __syncthreads();
#pragma unroll
    for (int kc = 0; kc < 2; ++kc) {
      bf16x8 af = *(const bf16x8*)&As[w * 16 + l16][kc * 32 + quad * 8];
#pragma unroll
      for (int nt = 0; nt < 4; ++nt) {
        bf16x8 bfv = *(const bf16x8*)&Bs[nt * 16 + l16][kc * 32 + quad * 8];
        acc[nt] = __builtin_amdgcn_mfma_f32_16x16x32_bf16(af, bfv, acc[nt], 0, 0, 0);
      }
    }
  }
#pragma unroll
  for (int r = 0; r < 4; ++r) {
    int mg = m0 + w * 16 + quad * 4 + r;
#pragma unroll
    for (int nt = 0; nt < 4; ++nt) {
      int ng = n0 + nt * 16 + l16;
      out[(size_t)mg * 512 + ng] = acc[nt][r] + bo[ng];
    }
  }
}

extern "C" void kernel_launch(void* const* d_in, const int* in_sizes, int n_in,
                              void* d_out, int out_size, void* d_ws, size_t ws_size,
                              hipStream_t stream) {
  const float* local = (const float*)d_in[0];
  const float* gfeat = (const float*)d_in[1];
  const float* Wq = (const float*)d_in[2];
  const float* bq = (const float*)d_in[3];
  const float* Wk = (const float*)d_in[4];
  const float* bk = (const float*)d_in[5];
  const float* Wv = (const float*)d_in[6];
  const float* bv = (const float*)d_in[7];
  const float* Wg = (const float*)d_in[8];
  const float* bg = (const float*)d_in[9];
  const float* Wo = (const float*)d_in[10];
  const float* bo = (const float*)d_in[11];

  char* w = (char*)d_ws;
  BF* Qb = (BF*)w;            w += (size_t)2097152 * 2;  // 4 MB (reused as ENH)
  BF* Kb = (BF*)w;            w += (size_t)8388608 * 2;  // 16 MB
  BF* VTb = (BF*)w;           w += (size_t)8388608 * 2;  // 16 MB (V^T [b,h,dh,key])
  BF* AO = (BF*)w;            w += (size_t)2097152 * 2;  // 4 MB (NS==1 only)
  // Region X: gfT (16 MB, dead after kv_k) aliases Opart (NS x 4 MB).
  BF* gfT = (BF*)w;
  BF* Opart = (BF*)w;
  size_t baseOff = (size_t)(w - (char*)d_ws);
  BF* ENH = Qb;

  int NS = 1;
  if (baseOff + 4 * (4194304 + 131072) <= ws_size) NS = 4;
  else if (baseOff + 16777216 + 2 * 131072 <= ws_size) NS = 2;
  float* lpart = (float*)(w + (size_t)NS * 4194304);

  dim3 blk(256);
  pre_k<<<dim3(2560), blk, 0, stream>>>(local, gfeat, Wq, bq, gfT, Qb);
  kv_k<<<dim3(1024), blk, 0, stream>>>(gfT, Wk, Wv, bk, bv, Kb, VTb);
  if (NS == 4) {
    attn_k<4><<<dim3(1024), blk, 0, stream>>>(Qb, Kb, VTb, AO, Opart, lpart);
    gate_k<4><<<dim3(64, 8), blk, 0, stream>>>(local, AO, Opart, lpart, Wg, bg, ENH);
  } else if (NS == 2) {
    attn_k<2><<<dim3(512), blk, 0, stream>>>(Qb, Kb, VTb, AO, Opart, lpart);
    gate_k<2><<<dim3(64, 8), blk, 0, stream>>>(local, AO, Opart, lpart, Wg, bg, ENH);
  } else {
    attn_k<1><<<dim3(256), blk, 0, stream>>>(Qb, Kb, VTb, AO, nullptr, nullptr);
    gate_k<1><<<dim3(64, 8), blk, 0, stream>>>(local, AO, Opart, lpart, Wg, bg, ENH);
  }
  out_k<<<dim3(64, 8), blk, 0, stream>>>(ENH, Wo, bo, (float*)d_out);
}

// Round 4
// 239.652 us; speedup vs baseline: 1.1082x; 1.0355x over previous
//
#include <hip/hip_runtime.h>
#include <hip/hip_bf16.h>
#include <cstdint>

typedef __hip_bfloat16 BF;
typedef unsigned short ushort_t;
typedef __attribute__((ext_vector_type(8))) __bf16 bf16x8;
typedef __attribute__((ext_vector_type(4))) float f32x4;
typedef __attribute__((ext_vector_type(4))) unsigned uint4v;

// Inputs/outputs are fp32 (established empirically rounds 2-9: detect flag
// always f32; fp32 output stores passed). Internal tensors bf16.
__device__ __forceinline__ float bu2f(ushort_t u) {
  return __uint_as_float((unsigned)u << 16);
}
__device__ __forceinline__ unsigned pk2(float a, float b) {
  union { __hip_bfloat162 h; unsigned u; } c;
  c.h = __float22bfloat162_rn(make_float2(a, b));  // v_cvt_pk_bf16_f32
  return c.u;
}
__device__ __forceinline__ unsigned short f2bu(float f) {
  union { BF b; unsigned short u; } c; c.b = __float2bfloat16(f); return c.u;
}
__device__ __forceinline__ float b2f(BF x) { return __bfloat162float(x); }
// 16 fp32 -> 16 bf16 bit patterns (8 packed converts).
__device__ __forceinline__ void rd16f(const float* fp, ushort_t* out) {
#pragma unroll
  for (int j = 0; j < 16; j += 4) {
    float4 v = *(const float4*)(fp + j);
    ((unsigned*)out)[j / 2] = pk2(v.x, v.y);
    ((unsigned*)out)[j / 2 + 1] = pk2(v.z, v.w);
  }
}

#define QS 0.1803368801111f  // (1/8)*log2(e): folded into Q so attn uses exp2

// ---------------------------------------------------------------------------
// prep_k (round-13): one-shot fp32->bf16 conversion of [local | Wq | Wk | Wv
// | Wg | Wo]. Same pk2 rounding as the old per-block rd16f staging ->
// bit-identical numerics downstream. Kills the redundant per-block,
// per-K-step conversions in all four GEMM kernels (every block was
// re-converting the same weight panel) and halves their global read bytes.
// ---------------------------------------------------------------------------
__global__ __launch_bounds__(256) void prep_k(const float* __restrict__ local,
                                              const float* __restrict__ Wq,
                                              const float* __restrict__ Wk,
                                              const float* __restrict__ Wv,
                                              const float* __restrict__ Wg,
                                              const float* __restrict__ Wo,
                                              BF* __restrict__ localB,
                                              BF* __restrict__ WB) {
  size_t e = ((size_t)blockIdx.x * 256 + threadIdx.x) * 16;
  const float* src;
  BF* dst;
  if (e < 2097152) {            // local: 4x1024x512
    src = local + e;  dst = localB + e;
  } else {
    size_t f = e - 2097152;     // weights, contiguous in WB
    dst = WB + f;
    if (f < 262144)        src = Wq + f;
    else if (f < 524288)   src = Wk + (f - 262144);
    else if (f < 786432)   src = Wv + (f - 524288);
    else if (f < 1310720)  src = Wg + (f - 786432);
    else                   src = Wo + (f - 1310720);
  }
  ushort_t vals[16];
  rd16f(src, vals);
  *(uint4*)dst = *(uint4*)&vals[0];
  *((uint4*)dst + 1) = *(uint4*)&vals[8];
}

// ---------------------------------------------------------------------------
// pre_k: fused [gfeat transpose+cvt] + [Q projection w/ RoPE].
// blocks [0,2048): gfT[bz][m][k] bf16 <- gfeat[bz][k][m] fp32.
// blocks [2048,2560): Q = RoPE(local @ Wq^T + bq) * QS, 64x64 tiles.
// Round-13: A/B staging reads pre-converted bf16 (localB/WqB) when present.
// ---------------------------------------------------------------------------
__global__ __launch_bounds__(256) void pre_k(const float* __restrict__ local,
                                             const float* __restrict__ gfeat,
                                             const float* __restrict__ Wq,
                                             const float* __restrict__ bq,
                                             const BF* __restrict__ localB,
                                             const BF* __restrict__ WqB,
                                             BF* __restrict__ gfT,
                                             BF* __restrict__ Qb) {
  __shared__ __align__(16) ushort_t smem[2][64][72];
  const int t = threadIdx.x;
  if (blockIdx.x < 2048) {
    auto T = smem[0];
    const int g = blockIdx.x;  // 4 bz x 64 mt x 8 kt
    const int bz = g & 3, mt = (g >> 2) & 63, kt = g >> 8;
    {
      int krow = t >> 2, mg = t & 3;
      ushort_t vals[16];
      rd16f(gfeat + (size_t)bz * 512 * 4096 + (size_t)(kt * 64 + krow) * 4096 +
                mt * 64 + mg * 16,
            vals);
#pragma unroll
      for (int j = 0; j < 16; ++j) T[mg * 16 + j][krow] = vals[j];
    }
    __syncthreads();
    int mrow = t >> 2, kg = t & 3;
    uint4 a = *(const uint4*)&T[mrow][kg * 16];
    uint4 b = *(const uint4*)&T[mrow][kg * 16 + 8];
    size_t o = ((size_t)bz * 4096 + mt * 64 + mrow) * 512 + kt * 64 + kg * 16;
    *(uint4*)&gfT[o] = a;
    *(uint4*)&gfT[o + 8] = b;
    return;
  }
  // ---- Q projection ----
  auto As = smem[0];
  auto Bs = smem[1];
  const int bx = blockIdx.x - 2048;
  const int m0 = (bx & 63) * 64, n0 = (bx >> 6) * 64;
  const int w = t >> 6, lane = t & 63;
  const int quad = lane >> 4, l16 = lane & 15;

  f32x4 acc[4] = {};
  for (int k0 = 0; k0 < 512; k0 += 64) {
    __syncthreads();
    {
      int row = t >> 2, cg = t & 3;
      int kg = k0 + cg * 16;
      if (WqB) {
        const uint4* pa = (const uint4*)(localB + (size_t)(m0 + row) * 512 + kg);
        *(uint4*)&As[row][cg * 16] = pa[0];
        *(uint4*)&As[row][cg * 16 + 8] = pa[1];
        const uint4* pb = (const uint4*)(WqB + (size_t)(n0 + row) * 512 + kg);
        *(uint4*)&Bs[row][cg * 16] = pb[0];
        *(uint4*)&Bs[row][cg * 16 + 8] = pb[1];
      } else {
        ushort_t vals[16];
        rd16f(local + (size_t)(m0 + row) * 512 + kg, vals);
        *(uint4*)&As[row][cg * 16] = *(uint4*)&vals[0];
        *(uint4*)&As[row][cg * 16 + 8] = *(uint4*)&vals[8];
        ushort_t bv[16];
        rd16f(Wq + (size_t)(n0 + row) * 512 + kg, bv);
        *(uint4*)&Bs[row][cg * 16] = *(uint4*)&bv[0];
        *(uint4*)&Bs[row][cg * 16 + 8] = *(uint4*)&bv[8];
      }
    }
    __syncthreads();
#pragma unroll
    for (int kc = 0; kc < 2; ++kc) {
      bf16x8 af = *(const bf16x8*)&As[w * 16 + l16][kc * 32 + quad * 8];
#pragma unroll
      for (int nt = 0; nt < 4; ++nt) {
        bf16x8 bfv = *(const bf16x8*)&Bs[nt * 16 + l16][kc * 32 + quad * 8];
        acc[nt] = __builtin_amdgcn_mfma_f32_16x16x32_bf16(af, bfv, acc[nt], 0, 0, 0);
      }
    }
  }
  const int head = n0 >> 6;
#pragma unroll
  for (int r = 0; r < 4; ++r) {
    int mg = m0 + w * 16 + quad * 4 + r;
    int bb = mg >> 10, qi = mg & 1023;
    float x = (float)(qi & 31) * (1.f / 31.f);
    float y = (float)(qi >> 5) * (1.f / 31.f);
    size_t base = (((size_t)bb * 8 + head) * 1024 + qi) * 64;
#pragma unroll
    for (int j = 0; j < 2; ++j) {
      int c0 = j * 16 + l16;
      float t0 = acc[j][r] + bq[head * 64 + c0];
      float t1 = acc[j + 2][r] + bq[head * 64 + c0 + 32];
      float fr = __expf((float)c0 * (-9.210340371976184f / 32.f));
      float ax = x * fr, ay = y * fr;
      Qb[base + c0] = __float2bfloat16((t0 * __cosf(ax) - t1 * __sinf(ax)) * QS);
      Qb[base + c0 + 32] = __float2bfloat16((t1 * __cosf(ay) + t0 * __sinf(ay)) * QS);
    }
  }
}

// ---------------------------------------------------------------------------
// kv_k: fused K/V projection from pre-transposed bf16 gfT. 128x128 tile,
// 1D XCD-pinned grid. n0<512 -> K+RoPE(global); else V -> V^T via LDS bounce.
// Round-13: B staging reads pre-converted bf16 WkB/WvB when present.
// ---------------------------------------------------------------------------
__global__ __launch_bounds__(256) void kv_k(const BF* __restrict__ gfT,
                                            const float* __restrict__ Wk,
                                            const float* __restrict__ Wv,
                                            const BF* __restrict__ WkB,
                                            const BF* __restrict__ WvB,
                                            const float* __restrict__ bk,
                                            const float* __restrict__ bv,
                                            BF* __restrict__ Kb,
                                            BF* __restrict__ VTb) {
  __shared__ __align__(16) ushort_t smem[2][128][72];
  auto As = smem[0];
  auto Bs = smem[1];
  const int tid = threadIdx.x;
  const int w = tid >> 6, lane = tid & 63;
  const int quad = lane >> 4, l16 = lane & 15;
  const int wm = w >> 1, wn = w & 1;
  const int g = blockIdx.x;
  const int a = g & 7, y = (g >> 3) & 7, bidx = g >> 6;
  const int m0 = ((bidx << 1) | (a & 1)) * 128;
  const int n0 = y * 128;
  const int bz = a >> 1;

  f32x4 acc[4][4] = {};
  for (int k0 = 0; k0 < 512; k0 += 64) {
    __syncthreads();
#pragma unroll
    for (int u = 0; u < 2; ++u) {  // A: bf16 row-major gfT, pure b128
      int unit = tid + u * 256;
      int row = unit >> 2, cg = unit & 3;
      const uint4* p = (const uint4*)(gfT + ((size_t)bz * 4096 + m0 + row) * 512 +
                                      k0 + cg * 16);
      *(uint4*)&As[row][cg * 16] = p[0];
      *(uint4*)&As[row][cg * 16 + 8] = p[1];
    }
    if (WkB) {  // B: pre-converted bf16 weights, pure b128
      const BF* bb16 = (n0 >= 512) ? WvB : WkB;
      const int nb = (n0 >= 512) ? (n0 - 512) : n0;
#pragma unroll
      for (int u = 0; u < 2; ++u) {
        int unit = tid + u * 256;
        int row = unit >> 2, cg = unit & 3;
        const uint4* p = (const uint4*)(bb16 + (size_t)(nb + row) * 512 +
                                        k0 + cg * 16);
        *(uint4*)&Bs[row][cg * 16] = p[0];
        *(uint4*)&Bs[row][cg * 16 + 8] = p[1];
      }
    } else {
#pragma unroll
      for (int u = 0; u < 2; ++u) {  // B: Wk or Wv (fp32)
        int unit = tid + u * 256;
        int row = unit >> 2, cg = unit & 3;
        const float* bsrc = (n0 >= 512) ? Wv : Wk;
        size_t nrow = (n0 >= 512) ? (n0 - 512 + row) : (n0 + row);
        ushort_t vals[16];
        rd16f(bsrc + nrow * 512 + k0 + cg * 16, vals);
        *(uint4*)&Bs[row][cg * 16] = *(uint4*)&vals[0];
        *(uint4*)&Bs[row][cg * 16 + 8] = *(uint4*)&vals[8];
      }
    }
    __syncthreads();
#pragma unroll
    for (int kc = 0; kc < 2; ++kc) {
      bf16x8 af[4], bfv[4];
#pragma unroll
      for (int i = 0; i < 4; ++i) {
        af[i] = *(const bf16x8*)&As[wm * 64 + i * 16 + l16][kc * 32 + quad * 8];
        bfv[i] = *(const bf16x8*)&Bs[wn * 64 + i * 16 + l16][kc * 32 + quad * 8];
      }
#pragma unroll
      for (int mt = 0; mt < 4; ++mt)
#pragma unroll
        for (int nt = 0; nt < 4; ++nt)
          acc[mt][nt] = __builtin_amdgcn_mfma_f32_16x16x32_bf16(af[mt], bfv[nt], acc[mt][nt], 0, 0, 0);
    }
  }
  if (n0 < 512) {  // K + RoPE(global)
    const int head = (n0 + wn * 64) >> 6;
#pragma unroll
    for (int mt = 0; mt < 4; ++mt)
#pragma unroll
      for (int r = 0; r < 4; ++r) {
        int pg = m0 + wm * 64 + mt * 16 + quad * 4 + r;
        float x = (float)(pg & 63) * (1.f / 63.f);
        float yy = (float)(pg >> 6) * (1.f / 63.f);
        size_t base = (((size_t)bz * 8 + head) * 4096 + pg) * 64;
#pragma unroll
        for (int j = 0; j < 2; ++j) {
          int c0 = j * 16 + l16;
          float t0 = acc[mt][j][r] + bk[head * 64 + c0];
          float t1 = acc[mt][j + 2][r] + bk[head * 64 + c0 + 32];
          float fr = __expf((float)c0 * (-9.210340371976184f / 32.f));
          float ax = x * fr, ay = yy * fr;
          Kb[base + c0] = __float2bfloat16(t0 * __cosf(ax) - t1 * __sinf(ax));
          Kb[base + c0 + 32] = __float2bfloat16(t1 * __cosf(ay) + t0 * __sinf(ay));
        }
      }
  } else {  // V -> V^T via LDS-bounce
    const int n0v = n0 - 512;
    __syncthreads();
    ushort_t (*T)[136] = (ushort_t(*)[136]) & smem[0][0][0];
#pragma unroll
    for (int mt = 0; mt < 4; ++mt)
#pragma unroll
      for (int nt = 0; nt < 4; ++nt)
#pragma unroll
        for (int r = 0; r < 4; ++r) {
          int n_l = wn * 64 + nt * 16 + l16;
          int m_l = wm * 64 + mt * 16 + quad * 4 + r;
          T[n_l][m_l] = f2bu(acc[mt][nt][r] + bv[n0v + n_l]);
        }
    __syncthreads();
    int row = tid >> 1, half = tid & 1;
    size_t gbase = (((size_t)bz * 8 + (n0v >> 6) + (row >> 6)) * 64 + (row & 63)) * 4096 +
                   m0 + half * 64;
    uint4* dst = (uint4*)(VTb + gbase);
    const uint4* src = (const uint4*)&T[row][half * 64];
#pragma unroll
    for (int j = 0; j < 8; ++j) dst[j] = src[j];
  }
}

// ---------------------------------------------------------------------------
// MFMA flash attention (round-12 structure, unchanged in round-13).
// ct-outer/nt-outer loops (16 b128 LDS reads/chunk = structural floor);
// key-bit-permuted V staging makes the S-output fragment directly the PV
// B-fragment (zero cross-lane moves). Double-buffered K/V, one
// barrier/chunk, register prefetch, exp2 softmax, XOR bank swizzle.
// ---------------------------------------------------------------------------
template <int NS>
__global__ __launch_bounds__(256, 4) void attn_k(const BF* __restrict__ Q,
                                                 const BF* __restrict__ K,
                                                 const BF* __restrict__ VT,
                                                 BF* __restrict__ AO,
                                                 BF* __restrict__ Opart,
                                                 float* __restrict__ lpart) {
  __shared__ __align__(16) ushort_t Ks[2][64][64];
  __shared__ __align__(16) ushort_t VTs[2][64][64];

  const int tid = threadIdx.x;
  const int w = tid >> 6, lane = tid & 63;
  const int quad = lane >> 4, l16 = lane & 15;
  // Swizzle: element chunk c (16B) of row r lives at chunk c ^ (r & 7).
  // All hot rows are (16k + l16), so row&7 == l16&7 (loop-invariant).
  const int r3 = l16 & 7;
  const int sc0 = (quad ^ r3) << 3;  // swizzled element col of orig chunk `quad`
  const int sc1 = sc0 ^ 32;          // orig chunk quad+4

  const int g = blockIdx.x;
  const int bh = g & 31;               // XCD = bh % 8 (K/V L2-pinned)
  const int qt = (g >> 5) & 7;
  const int ks = g >> 8;
  const int b = bh >> 3, h = bh & 7;
  const int q0 = qt * 128 + w * 32;
  const int kspan = 4096 / NS, kbase = ks * kspan;

  bf16x8 qa[2][2];
#pragma unroll
  for (int qs = 0; qs < 2; ++qs) {
    const BF* qp = Q + (((size_t)bh << 10) + q0 + qs * 16 + l16) * 64 + quad * 8;
    qa[qs][0] = *(const bf16x8*)qp;
    qa[qs][1] = *(const bf16x8*)(qp + 32);
  }
  bf16x8 ones;
#pragma unroll
  for (int j = 0; j < 8; ++j) ones[j] = (__bf16)1.0f;

  const BF* Kp = K + (size_t)bh * 4096 * 64;    // [key][dh]
  const BF* VTp = VT + (size_t)bh * 64 * 4096;  // [dh][key]

  f32x4 o[2][4] = {};
  f32x4 ol[2] = {};

  const int srow = tid >> 2, scol = (tid & 3) * 16;
  const int ssc = ((2 * (tid & 3)) ^ (srow & 7)) << 3;  // K swizzled store col
  // V store columns: global key g (16 per thread) lands at logical position
  // p = s1*32 + t3*16 + t2*8 + s0*4 + (t&3)  (s1s0 = tid&3, t = g&15),
  // i.e. 4 b64 groups; physical col applies the 16B-chunk XOR swizzle.
  int vcol[4];
  {
    const int s1 = (tid >> 1) & 1, s0v = tid & 1;
#pragma unroll
    for (int gq = 0; gq < 4; ++gq)
      vcol[gq] = (((s1 * 4 + gq) ^ (srow & 7)) << 3) + s0v * 4;
  }

#define STAGE_V(buf, v0, v1)                                   \
  {                                                            \
    uint2 t_;                                                  \
    t_.x = (v0).x; t_.y = (v0).y; *(uint2*)&VTs[buf][srow][vcol[0]] = t_; \
    t_.x = (v0).z; t_.y = (v0).w; *(uint2*)&VTs[buf][srow][vcol[1]] = t_; \
    t_.x = (v1).x; t_.y = (v1).y; *(uint2*)&VTs[buf][srow][vcol[2]] = t_; \
    t_.x = (v1).z; t_.y = (v1).w; *(uint2*)&VTs[buf][srow][vcol[3]] = t_; \
  }

  {  // prologue: stage chunk 0 into buffer 0
    const uint4* kp = (const uint4*)(Kp + (size_t)(kbase + srow) * 64 + scol);
    const uint4* vp = (const uint4*)(VTp + (size_t)srow * 4096 + kbase + scol);
    uint4 a = kp[0], bb = kp[1], c = vp[0], d = vp[1];
    *(uint4*)&Ks[0][srow][ssc] = a;  *(uint4*)&Ks[0][srow][ssc ^ 8] = bb;
    STAGE_V(0, c, d);
  }
  __syncthreads();

  const int nc = kspan / 64;
  for (int c = 0; c < nc; ++c) {
    const int cur = c & 1;
    uint4 nk0, nk1, nv0, nv1;
    const bool more = (c + 1 < nc);
    if (more) {  // issue next chunk's global loads early (hide under compute)
      const int c1 = kbase + (c + 1) * 64;
      const uint4* kp = (const uint4*)(Kp + (size_t)(c1 + srow) * 64 + scol);
      const uint4* vp = (const uint4*)(VTp + (size_t)srow * 4096 + c1 + scol);
      nk0 = kp[0]; nk1 = kp[1]; nv0 = vp[0]; nv1 = vp[1];
    }

    // ---- S^T = K Q^T ; P = exp2(S^T) packed straight into PV B-fragments ----
    unsigned pa_u[2][2][4];  // [qs][ks32][word]
#pragma unroll
    for (int ct = 0; ct < 4; ++ct) {
      const int krow = ct * 16 + l16;
      bf16x8 kb0 = *(const bf16x8*)&Ks[cur][krow][sc0];
      bf16x8 kb1 = *(const bf16x8*)&Ks[cur][krow][sc1];
#pragma unroll
      for (int qs = 0; qs < 2; ++qs) {
        f32x4 s = {};
        __builtin_amdgcn_s_setprio(1);
        s = __builtin_amdgcn_mfma_f32_16x16x32_bf16(kb0, qa[qs][0], s, 0, 0, 0);
        s = __builtin_amdgcn_mfma_f32_16x16x32_bf16(kb1, qa[qs][1], s, 0, 0, 0);
        __builtin_amdgcn_s_setprio(0);
        pa_u[qs][ct >> 1][(ct & 1) * 2] =
            pk2(__builtin_exp2f(s[0]), __builtin_exp2f(s[1]));
        pa_u[qs][ct >> 1][(ct & 1) * 2 + 1] =
            pk2(__builtin_exp2f(s[2]), __builtin_exp2f(s[3]));
      }
    }
    bf16x8 pa[2][2];
#pragma unroll
    for (int qs = 0; qs < 2; ++qs)
#pragma unroll
      for (int kk = 0; kk < 2; ++kk) {
        uint4v u = {pa_u[qs][kk][0], pa_u[qs][kk][1], pa_u[qs][kk][2],
                    pa_u[qs][kk][3]};
        pa[qs][kk] = __builtin_bit_cast(bf16x8, u);
      }

    // ---- O^T += V^T P^T ; l += 1^T P^T (each vb read feeds both qs) ----
    __builtin_amdgcn_s_setprio(1);
#pragma unroll
    for (int qs = 0; qs < 2; ++qs) {
      ol[qs] = __builtin_amdgcn_mfma_f32_16x16x32_bf16(ones, pa[qs][0], ol[qs], 0, 0, 0);
      ol[qs] = __builtin_amdgcn_mfma_f32_16x16x32_bf16(ones, pa[qs][1], ol[qs], 0, 0, 0);
    }
#pragma unroll
    for (int nt = 0; nt < 4; ++nt) {
      const int vrow = nt * 16 + l16;
      bf16x8 vb0 = *(const bf16x8*)&VTs[cur][vrow][sc0];
      bf16x8 vb1 = *(const bf16x8*)&VTs[cur][vrow][sc1];
#pragma unroll
      for (int qs = 0; qs < 2; ++qs) {
        o[qs][nt] = __builtin_amdgcn_mfma_f32_16x16x32_bf16(vb0, pa[qs][0], o[qs][nt], 0, 0, 0);
        o[qs][nt] = __builtin_amdgcn_mfma_f32_16x16x32_bf16(vb1, pa[qs][1], o[qs][nt], 0, 0, 0);
      }
    }
    __builtin_amdgcn_s_setprio(0);

    if (more) {  // write next chunk into the other buffer (T14 late-write)
      *(uint4*)&Ks[cur ^ 1][srow][ssc] = nk0;
      *(uint4*)&Ks[cur ^ 1][srow][ssc ^ 8] = nk1;
      STAGE_V(cur ^ 1, nv0, nv1);
    }
    __syncthreads();  // single barrier per chunk (dbuf makes 2nd unnecessary)
  }
#undef STAGE_V

  // ---- epilogue: lane holds O^T[dh = nt*16+quad*4+r][q = l16] ----
#pragma unroll
  for (int qs = 0; qs < 2; ++qs) {
    int qg = q0 + qs * 16 + l16;
    if (NS == 1) {
      float invl = 1.f / ol[qs][0];
#pragma unroll
      for (int nt = 0; nt < 4; ++nt) {
        uint2 uu;
        uu.x = pk2(o[qs][nt][0] * invl, o[qs][nt][1] * invl);
        uu.y = pk2(o[qs][nt][2] * invl, o[qs][nt][3] * invl);
        *(uint2*)(AO + (((size_t)b << 10) + qg) * 512 + h * 64 + nt * 16 + quad * 4) = uu;
      }
    } else {
      if (quad == 0) lpart[ks * 32768 + (bh << 10) + qg] = ol[qs][0];
#pragma unroll
      for (int nt = 0; nt < 4; ++nt) {
        uint2 uu;
        uu.x = pk2(o[qs][nt][0], o[qs][nt][1]);
        uu.y = pk2(o[qs][nt][2], o[qs][nt][3]);
        *(uint2*)(Opart + (size_t)ks * 2097152 + (((size_t)bh << 10) + qg) * 64 +
                  nt * 16 + quad * 4) = uu;
      }
    }
  }
}

// ---------------------------------------------------------------------------
// gate_k: gate GEMM (K=1024, A=[local | AO]) + sigmoid-gate epilogue.
// The NS-way K-split merge is FUSED into A-staging (kg>=512 path reads
// Opart/lpart and merges inline) — no reduce_k launch, no AO roundtrip.
// The AO tile needed by the epilogue is captured from LDS at k0==512+n0.
// Round-13: kg<512 A-staging and B-staging read pre-converted bf16.
// ---------------------------------------------------------------------------
template <int NS>
__global__ __launch_bounds__(256) void gate_k(const float* __restrict__ local,
                                              const BF* __restrict__ localB,
                                              const BF* __restrict__ AO,
                                              const BF* __restrict__ Opart,
                                              const float* __restrict__ lpart,
                                              const float* __restrict__ Wg,
                                              const BF* __restrict__ WgB,
                                              const float* __restrict__ bg,
                                              BF* __restrict__ ENH) {
  __shared__ __align__(16) ushort_t As[64][72];
  __shared__ __align__(16) ushort_t Bs[64][72];
  const int tid = threadIdx.x;
  const int w = tid >> 6, lane = tid & 63;
  const int quad = lane >> 4, l16 = lane & 15;
  const int m0 = blockIdx.x * 64, n0 = blockIdx.y * 64;

  f32x4 acc[4] = {};
  float aosv[4][4];  // AO values for epilogue, captured from As
  for (int k0 = 0; k0 < 1024; k0 += 64) {
    __syncthreads();
    {
      int row = tid >> 2, cg = tid & 3;
      int kg = k0 + cg * 16;
      ushort_t vals[16];
      if (kg < 512) {
        if (localB) {
          const uint4* p = (const uint4*)(localB + (size_t)(m0 + row) * 512 + kg);
          *(uint4*)&vals[0] = p[0]; *(uint4*)&vals[8] = p[1];
        } else {
          rd16f(local + (size_t)(m0 + row) * 512 + kg, vals);
        }
      } else {
        int c = kg - 512;               // 16-aligned, single head per unit
        int hh = c >> 6, dh0 = c & 63;
        int mg = m0 + row;
        size_t bq = (size_t)(((mg >> 10) * 8 + hh) << 10) + (mg & 1023);
        if (NS == 1) {
          const uint4* p = (const uint4*)(AO + (size_t)mg * 512 + c);
          *(uint4*)&vals[0] = p[0]; *(uint4*)&vals[8] = p[1];
        } else {
          float ls = 0.f;
#pragma unroll
          for (int s2 = 0; s2 < NS; ++s2) ls += lpart[s2 * 32768 + bq];
          float inv = 1.f / ls;
          float av[16] = {};
#pragma unroll
          for (int s2 = 0; s2 < NS; ++s2) {
            const ushort_t* op = (const ushort_t*)Opart + (size_t)s2 * 2097152 +
                                 bq * 64 + dh0;
            uint4 u0 = ((const uint4*)op)[0], u1 = ((const uint4*)op)[1];
            const ushort_t* pu = (const ushort_t*)&u0;
#pragma unroll
            for (int j = 0; j < 8; ++j) av[j] += bu2f(pu[j]);
            pu = (const ushort_t*)&u1;
#pragma unroll
            for (int j = 0; j < 8; ++j) av[8 + j] += bu2f(pu[j]);
          }
#pragma unroll
          for (int j = 0; j < 16; j += 2)
            ((unsigned*)vals)[j / 2] = pk2(av[j] * inv, av[j + 1] * inv);
        }
      }
      *(uint4*)&As[row][cg * 16] = *(uint4*)&vals[0];
      *(uint4*)&As[row][cg * 16 + 8] = *(uint4*)&vals[8];
      if (WgB) {
        const uint4* p = (const uint4*)(WgB + (size_t)(n0 + row) * 1024 + kg);
        *(uint4*)&Bs[row][cg * 16] = p[0];
        *(uint4*)&Bs[row][cg * 16 + 8] = p[1];
      } else {
        ushort_t bv[16];
        rd16f(Wg + (size_t)(n0 + row) * 1024 + kg, bv);
        *(uint4*)&Bs[row][cg * 16] = *(uint4*)&bv[0];
        *(uint4*)&Bs[row][cg * 16 + 8] = *(uint4*)&bv[8];
      }
    }
    __syncthreads();
    if (k0 == 512 + n0) {  // capture this block's AO tile for the epilogue
#pragma unroll
      for (int r = 0; r < 4; ++r)
#pragma unroll
        for (int nt = 0; nt < 4; ++nt)
          aosv[r][nt] = bu2f(As[w * 16 + quad * 4 + r][nt * 16 + l16]);
    }
#pragma unroll
    for (int kc = 0; kc < 2; ++kc) {
      bf16x8 af = *(const bf16x8*)&As[w * 16 + l16][kc * 32 + quad * 8];
#pragma unroll
      for (int nt = 0; nt < 4; ++nt) {
        bf16x8 bfv = *(const bf16x8*)&Bs[nt * 16 + l16][kc * 32 + quad * 8];
        acc[nt] = __builtin_amdgcn_mfma_f32_16x16x32_bf16(af, bfv, acc[nt], 0, 0, 0);
      }
    }
  }
#pragma unroll
  for (int r = 0; r < 4; ++r) {
    int mg = m0 + w * 16 + quad * 4 + r;
#pragma unroll
    for (int nt = 0; nt < 4; ++nt) {
      int ng = n0 + nt * 16 + l16;
      size_t idx = (size_t)mg * 512 + ng;
      float gg = 1.f / (1.f + __expf(-(acc[nt][r] + bg[ng])));
      ENH[idx] = __float2bfloat16(local[idx] + gg * aosv[r][nt]);
    }
  }
}

// ---------------------------------------------------------------------------
// out_k: final projection, fp32 output.
// Round-13: B staging reads pre-converted bf16 WoB when present.
// ---------------------------------------------------------------------------
__global__ __launch_bounds__(256) void out_k(const BF* __restrict__ ENH,
                                             const float* __restrict__ Wo,
                                             const BF* __restrict__ WoB,
                                             const float* __restrict__ bo,
                                             float* __restrict__ out) {
  __shared__ __align__(16) ushort_t As[64][72];
  __shared__ __align__(16) ushort_t Bs[64][72];
  const int tid = threadIdx.x;
  const int w = tid >> 6, lane = tid & 63;
  const int quad = lane >> 4, l16 = lane & 15;
  const int m0 = blockIdx.x * 64, n0 = blockIdx.y * 64;

  f32x4 acc[4] = {};
  for (int k0 = 0; k0 < 512; k0 += 64) {
    __syncthreads();
    {
      int row = tid >> 2, cg = tid & 3;
      int kg = k0 + cg * 16;
      const uint4* p = (const uint4*)(ENH + (size_t)(m0 + row) * 512 + kg);
      *(uint4*)&As[row][cg * 16] = p[0];
      *(uint4*)&As[row][cg * 16 + 8] = p[1];
      if (WoB) {
        const uint4* pb = (const uint4*)(WoB + (size_t)(n0 + row) * 512 + kg);
        *(uint4*)&Bs[row][cg * 16] = pb[0];
        *(uint4*)&Bs[row][cg * 16 + 8] = pb[1];
      } else {
        ushort_t bv[16];
        rd16f(Wo + (size_t)(n0 + row) * 512 + kg, bv);
        *(uint4*)&Bs[row][cg * 16] = *(uint4*)&bv[0];
        *(uint4*)&Bs[row][cg * 16 + 8] = *(uint4*)&bv[8];
      }
    }
    __syncthreads();
#pragma unroll
    for (int kc = 0; kc < 2; ++kc) {
      bf16x8 af = *(const bf16x8*)&As[w * 16 + l16][kc * 32 + quad * 8];
#pragma unroll
      for (int nt = 0; nt < 4; ++nt) {
        bf16x8 bfv = *(const bf16x8*)&Bs[nt * 16 + l16][kc * 32 + quad * 8];
        acc[nt] = __builtin_amdgcn_mfma_f32_16x16x32_bf16(af, bfv, acc[nt], 0, 0, 0);
      }
    }
  }
#pragma unroll
  for (int r = 0; r < 4; ++r) {
    int mg = m0 + w * 16 + quad * 4 + r;
#pragma unroll
    for (int nt = 0; nt < 4; ++nt) {
      int ng = n0 + nt * 16 + l16;
      out[(size_t)mg * 512 + ng] = acc[nt][r] + bo[ng];
    }
  }
}

extern "C" void kernel_launch(void* const* d_in, const int* in_sizes, int n_in,
                              void* d_out, int out_size, void* d_ws, size_t ws_size,
                              hipStream_t stream) {
  const float* local = (const float*)d_in[0];
  const float* gfeat = (const float*)d_in[1];
  const float* Wq = (const float*)d_in[2];
  const float* bq = (const float*)d_in[3];
  const float* Wk = (const float*)d_in[4];
  const float* bk = (const float*)d_in[5];
  const float* Wv = (const float*)d_in[6];
  const float* bv = (const float*)d_in[7];
  const float* Wg = (const float*)d_in[8];
  const float* bg = (const float*)d_in[9];
  const float* Wo = (const float*)d_in[10];
  const float* bo = (const float*)d_in[11];

  char* w = (char*)d_ws;
  BF* Qb = (BF*)w;            w += (size_t)2097152 * 2;  // 4 MB (reused as ENH)
  BF* Kb = (BF*)w;            w += (size_t)8388608 * 2;  // 16 MB
  BF* VTb = (BF*)w;           w += (size_t)8388608 * 2;  // 16 MB (V^T [b,h,dh,key])
  BF* AO = (BF*)w;            w += (size_t)2097152 * 2;  // 4 MB (NS==1 only)
  // Region X: gfT (16 MB, dead after kv_k) aliases Opart (NS x 4 MB).
  BF* gfT = (BF*)w;
  BF* Opart = (BF*)w;
  size_t baseOff = (size_t)(w - (char*)d_ws);
  BF* ENH = Qb;

  int NS = 1;
  if (baseOff + 4 * (4194304 + 131072) <= ws_size) NS = 4;
  else if (baseOff + 16777216 + 2 * 131072 <= ws_size) NS = 2;
  float* lpart = (float*)(w + (size_t)NS * 4194304);

  // Round-13: bf16 prep region (weights 3 MB + localB 4 MB) after region X.
  size_t xsize = (size_t)NS * (4194304 + 131072);
  if (xsize < 16777216) xsize = 16777216;  // gfT aliases region X start
  BF* WB = (BF*)(w + xsize);
  BF* localB = WB + 1572864;
  bool useP = (baseOff + xsize + 3145728 + 4194304) <= ws_size;
  const BF *WqB = nullptr, *WkB = nullptr, *WvB = nullptr, *WgB = nullptr,
           *WoB = nullptr, *locB = nullptr;
  if (useP) {
    WqB = WB;            WkB = WB + 262144;  WvB = WB + 524288;
    WgB = WB + 786432;   WoB = WB + 1310720; locB = localB;
  }

  dim3 blk(256);
  if (useP)
    prep_k<<<dim3(896), blk, 0, stream>>>(local, Wq, Wk, Wv, Wg, Wo, localB, WB);
  pre_k<<<dim3(2560), blk, 0, stream>>>(local, gfeat, Wq, bq, locB, WqB, gfT, Qb);
  kv_k<<<dim3(1024), blk, 0, stream>>>(gfT, Wk, Wv, WkB, WvB, bk, bv, Kb, VTb);
  if (NS == 4) {
    attn_k<4><<<dim3(1024), blk, 0, stream>>>(Qb, Kb, VTb, AO, Opart, lpart);
    gate_k<4><<<dim3(64, 8), blk, 0, stream>>>(local, locB, AO, Opart, lpart, Wg, WgB, bg, ENH);
  } else if (NS == 2) {
    attn_k<2><<<dim3(512), blk, 0, stream>>>(Qb, Kb, VTb, AO, Opart, lpart);
    gate_k<2><<<dim3(64, 8), blk, 0, stream>>>(local, locB, AO, Opart, lpart, Wg, WgB, bg, ENH);
  } else {
    attn_k<1><<<dim3(256), blk, 0, stream>>>(Qb, Kb, VTb, AO, nullptr, nullptr);
    gate_k<1><<<dim3(64, 8), blk, 0, stream>>>(local, locB, AO, Opart, lpart, Wg, WgB, bg, ENH);
  }
  out_k<<<dim3(64, 8), blk, 0, stream>>>(ENH, Wo, WoB, bo, (float*)d_out);
}

// Round 5
// 238.722 us; speedup vs baseline: 1.1125x; 1.0039x over previous
//
#include <hip/hip_runtime.h>
#include <hip/hip_bf16.h>
#include <cstdint>

typedef __hip_bfloat16 BF;
typedef unsigned short ushort_t;
typedef __attribute__((ext_vector_type(8))) __bf16 bf16x8;
typedef __attribute__((ext_vector_type(4))) float f32x4;
typedef __attribute__((ext_vector_type(4))) unsigned uint4v;

// Inputs/outputs are fp32 (established empirically rounds 2-9: detect flag
// always f32; fp32 output stores passed). Internal tensors bf16.
__device__ __forceinline__ float bu2f(ushort_t u) {
  return __uint_as_float((unsigned)u << 16);
}
__device__ __forceinline__ unsigned pk2(float a, float b) {
  union { __hip_bfloat162 h; unsigned u; } c;
  c.h = __float22bfloat162_rn(make_float2(a, b));  // v_cvt_pk_bf16_f32
  return c.u;
}
__device__ __forceinline__ unsigned short f2bu(float f) {
  union { BF b; unsigned short u; } c; c.b = __float2bfloat16(f); return c.u;
}
__device__ __forceinline__ float b2f(BF x) { return __bfloat162float(x); }
// 16 fp32 -> 16 bf16 bit patterns (8 packed converts).
__device__ __forceinline__ void rd16f(const float* fp, ushort_t* out) {
#pragma unroll
  for (int j = 0; j < 16; j += 4) {
    float4 v = *(const float4*)(fp + j);
    ((unsigned*)out)[j / 2] = pk2(v.x, v.y);
    ((unsigned*)out)[j / 2 + 1] = pk2(v.z, v.w);
  }
}

#define QS 0.1803368801111f  // (1/8)*log2(e): folded into Q so attn uses exp2

// ---------------------------------------------------------------------------
// prep_k (round-13): one-shot fp32->bf16 conversion of [local | Wq | Wk | Wv
// | Wg | Wo]. Same pk2 rounding as the old per-block rd16f staging ->
// bit-identical numerics downstream.
// ---------------------------------------------------------------------------
__global__ __launch_bounds__(256) void prep_k(const float* __restrict__ local,
                                              const float* __restrict__ Wq,
                                              const float* __restrict__ Wk,
                                              const float* __restrict__ Wv,
                                              const float* __restrict__ Wg,
                                              const float* __restrict__ Wo,
                                              BF* __restrict__ localB,
                                              BF* __restrict__ WB) {
  size_t e = ((size_t)blockIdx.x * 256 + threadIdx.x) * 16;
  const float* src;
  BF* dst;
  if (e < 2097152) {            // local: 4x1024x512
    src = local + e;  dst = localB + e;
  } else {
    size_t f = e - 2097152;     // weights, contiguous in WB
    dst = WB + f;
    if (f < 262144)        src = Wq + f;
    else if (f < 524288)   src = Wk + (f - 262144);
    else if (f < 786432)   src = Wv + (f - 524288);
    else if (f < 1310720)  src = Wg + (f - 786432);
    else                   src = Wo + (f - 1310720);
  }
  ushort_t vals[16];
  rd16f(src, vals);
  *(uint4*)dst = *(uint4*)&vals[0];
  *((uint4*)dst + 1) = *(uint4*)&vals[8];
}

// ---------------------------------------------------------------------------
// pre_k: fused [gfeat transpose+cvt] + [Q projection w/ RoPE].
// blocks [0,2048): gfT[bz][m][k] bf16 <- gfeat[bz][k][m] fp32.
// blocks [2048,2560): Q = RoPE(local @ Wq^T + bq) * QS, 64x64 tiles.
// Round-13: A/B staging reads pre-converted bf16 (localB/WqB) when present.
// ---------------------------------------------------------------------------
__global__ __launch_bounds__(256) void pre_k(const float* __restrict__ local,
                                             const float* __restrict__ gfeat,
                                             const float* __restrict__ Wq,
                                             const float* __restrict__ bq,
                                             const BF* __restrict__ localB,
                                             const BF* __restrict__ WqB,
                                             BF* __restrict__ gfT,
                                             BF* __restrict__ Qb) {
  __shared__ __align__(16) ushort_t smem[2][64][72];
  const int t = threadIdx.x;
  if (blockIdx.x < 2048) {
    auto T = smem[0];
    const int g = blockIdx.x;  // 4 bz x 64 mt x 8 kt
    const int bz = g & 3, mt = (g >> 2) & 63, kt = g >> 8;
    {
      int krow = t >> 2, mg = t & 3;
      ushort_t vals[16];
      rd16f(gfeat + (size_t)bz * 512 * 4096 + (size_t)(kt * 64 + krow) * 4096 +
                mt * 64 + mg * 16,
            vals);
#pragma unroll
      for (int j = 0; j < 16; ++j) T[mg * 16 + j][krow] = vals[j];
    }
    __syncthreads();
    int mrow = t >> 2, kg = t & 3;
    uint4 a = *(const uint4*)&T[mrow][kg * 16];
    uint4 b = *(const uint4*)&T[mrow][kg * 16 + 8];
    size_t o = ((size_t)bz * 4096 + mt * 64 + mrow) * 512 + kt * 64 + kg * 16;
    *(uint4*)&gfT[o] = a;
    *(uint4*)&gfT[o + 8] = b;
    return;
  }
  // ---- Q projection ----
  auto As = smem[0];
  auto Bs = smem[1];
  const int bx = blockIdx.x - 2048;
  const int m0 = (bx & 63) * 64, n0 = (bx >> 6) * 64;
  const int w = t >> 6, lane = t & 63;
  const int quad = lane >> 4, l16 = lane & 15;

  f32x4 acc[4] = {};
  for (int k0 = 0; k0 < 512; k0 += 64) {
    __syncthreads();
    {
      int row = t >> 2, cg = t & 3;
      int kg = k0 + cg * 16;
      if (WqB) {
        const uint4* pa = (const uint4*)(localB + (size_t)(m0 + row) * 512 + kg);
        *(uint4*)&As[row][cg * 16] = pa[0];
        *(uint4*)&As[row][cg * 16 + 8] = pa[1];
        const uint4* pb = (const uint4*)(WqB + (size_t)(n0 + row) * 512 + kg);
        *(uint4*)&Bs[row][cg * 16] = pb[0];
        *(uint4*)&Bs[row][cg * 16 + 8] = pb[1];
      } else {
        ushort_t vals[16];
        rd16f(local + (size_t)(m0 + row) * 512 + kg, vals);
        *(uint4*)&As[row][cg * 16] = *(uint4*)&vals[0];
        *(uint4*)&As[row][cg * 16 + 8] = *(uint4*)&vals[8];
        ushort_t bv[16];
        rd16f(Wq + (size_t)(n0 + row) * 512 + kg, bv);
        *(uint4*)&Bs[row][cg * 16] = *(uint4*)&bv[0];
        *(uint4*)&Bs[row][cg * 16 + 8] = *(uint4*)&bv[8];
      }
    }
    __syncthreads();
#pragma unroll
    for (int kc = 0; kc < 2; ++kc) {
      bf16x8 af = *(const bf16x8*)&As[w * 16 + l16][kc * 32 + quad * 8];
#pragma unroll
      for (int nt = 0; nt < 4; ++nt) {
        bf16x8 bfv = *(const bf16x8*)&Bs[nt * 16 + l16][kc * 32 + quad * 8];
        acc[nt] = __builtin_amdgcn_mfma_f32_16x16x32_bf16(af, bfv, acc[nt], 0, 0, 0);
      }
    }
  }
  const int head = n0 >> 6;
#pragma unroll
  for (int r = 0; r < 4; ++r) {
    int mg = m0 + w * 16 + quad * 4 + r;
    int bb = mg >> 10, qi = mg & 1023;
    float x = (float)(qi & 31) * (1.f / 31.f);
    float y = (float)(qi >> 5) * (1.f / 31.f);
    size_t base = (((size_t)bb * 8 + head) * 1024 + qi) * 64;
#pragma unroll
    for (int j = 0; j < 2; ++j) {
      int c0 = j * 16 + l16;
      float t0 = acc[j][r] + bq[head * 64 + c0];
      float t1 = acc[j + 2][r] + bq[head * 64 + c0 + 32];
      float fr = __expf((float)c0 * (-9.210340371976184f / 32.f));
      float ax = x * fr, ay = y * fr;
      Qb[base + c0] = __float2bfloat16((t0 * __cosf(ax) - t1 * __sinf(ax)) * QS);
      Qb[base + c0 + 32] = __float2bfloat16((t1 * __cosf(ay) + t0 * __sinf(ay)) * QS);
    }
  }
}

// ---------------------------------------------------------------------------
// kv_k: fused K/V projection from pre-transposed bf16 gfT. 128x128 tile,
// 1D XCD-pinned grid. n0<512 -> K+RoPE(global); else V -> V^T via LDS bounce.
// Round-13: B staging reads pre-converted bf16 WkB/WvB when present.
// ---------------------------------------------------------------------------
__global__ __launch_bounds__(256) void kv_k(const BF* __restrict__ gfT,
                                            const float* __restrict__ Wk,
                                            const float* __restrict__ Wv,
                                            const BF* __restrict__ WkB,
                                            const BF* __restrict__ WvB,
                                            const float* __restrict__ bk,
                                            const float* __restrict__ bv,
                                            BF* __restrict__ Kb,
                                            BF* __restrict__ VTb) {
  __shared__ __align__(16) ushort_t smem[2][128][72];
  auto As = smem[0];
  auto Bs = smem[1];
  const int tid = threadIdx.x;
  const int w = tid >> 6, lane = tid & 63;
  const int quad = lane >> 4, l16 = lane & 15;
  const int wm = w >> 1, wn = w & 1;
  const int g = blockIdx.x;
  const int a = g & 7, y = (g >> 3) & 7, bidx = g >> 6;
  const int m0 = ((bidx << 1) | (a & 1)) * 128;
  const int n0 = y * 128;
  const int bz = a >> 1;

  f32x4 acc[4][4] = {};
  for (int k0 = 0; k0 < 512; k0 += 64) {
    __syncthreads();
#pragma unroll
    for (int u = 0; u < 2; ++u) {  // A: bf16 row-major gfT, pure b128
      int unit = tid + u * 256;
      int row = unit >> 2, cg = unit & 3;
      const uint4* p = (const uint4*)(gfT + ((size_t)bz * 4096 + m0 + row) * 512 +
                                      k0 + cg * 16);
      *(uint4*)&As[row][cg * 16] = p[0];
      *(uint4*)&As[row][cg * 16 + 8] = p[1];
    }
    if (WkB) {  // B: pre-converted bf16 weights, pure b128
      const BF* bb16 = (n0 >= 512) ? WvB : WkB;
      const int nb = (n0 >= 512) ? (n0 - 512) : n0;
#pragma unroll
      for (int u = 0; u < 2; ++u) {
        int unit = tid + u * 256;
        int row = unit >> 2, cg = unit & 3;
        const uint4* p = (const uint4*)(bb16 + (size_t)(nb + row) * 512 +
                                        k0 + cg * 16);
        *(uint4*)&Bs[row][cg * 16] = p[0];
        *(uint4*)&Bs[row][cg * 16 + 8] = p[1];
      }
    } else {
#pragma unroll
      for (int u = 0; u < 2; ++u) {  // B: Wk or Wv (fp32)
        int unit = tid + u * 256;
        int row = unit >> 2, cg = unit & 3;
        const float* bsrc = (n0 >= 512) ? Wv : Wk;
        size_t nrow = (n0 >= 512) ? (n0 - 512 + row) : (n0 + row);
        ushort_t vals[16];
        rd16f(bsrc + nrow * 512 + k0 + cg * 16, vals);
        *(uint4*)&Bs[row][cg * 16] = *(uint4*)&vals[0];
        *(uint4*)&Bs[row][cg * 16 + 8] = *(uint4*)&vals[8];
      }
    }
    __syncthreads();
#pragma unroll
    for (int kc = 0; kc < 2; ++kc) {
      bf16x8 af[4], bfv[4];
#pragma unroll
      for (int i = 0; i < 4; ++i) {
        af[i] = *(const bf16x8*)&As[wm * 64 + i * 16 + l16][kc * 32 + quad * 8];
        bfv[i] = *(const bf16x8*)&Bs[wn * 64 + i * 16 + l16][kc * 32 + quad * 8];
      }
#pragma unroll
      for (int mt = 0; mt < 4; ++mt)
#pragma unroll
        for (int nt = 0; nt < 4; ++nt)
          acc[mt][nt] = __builtin_amdgcn_mfma_f32_16x16x32_bf16(af[mt], bfv[nt], acc[mt][nt], 0, 0, 0);
    }
  }
  if (n0 < 512) {  // K + RoPE(global)
    const int head = (n0 + wn * 64) >> 6;
#pragma unroll
    for (int mt = 0; mt < 4; ++mt)
#pragma unroll
      for (int r = 0; r < 4; ++r) {
        int pg = m0 + wm * 64 + mt * 16 + quad * 4 + r;
        float x = (float)(pg & 63) * (1.f / 63.f);
        float yy = (float)(pg >> 6) * (1.f / 63.f);
        size_t base = (((size_t)bz * 8 + head) * 4096 + pg) * 64;
#pragma unroll
        for (int j = 0; j < 2; ++j) {
          int c0 = j * 16 + l16;
          float t0 = acc[mt][j][r] + bk[head * 64 + c0];
          float t1 = acc[mt][j + 2][r] + bk[head * 64 + c0 + 32];
          float fr = __expf((float)c0 * (-9.210340371976184f / 32.f));
          float ax = x * fr, ay = yy * fr;
          Kb[base + c0] = __float2bfloat16(t0 * __cosf(ax) - t1 * __sinf(ax));
          Kb[base + c0 + 32] = __float2bfloat16(t1 * __cosf(ay) + t0 * __sinf(ay));
        }
      }
  } else {  // V -> V^T via LDS-bounce
    const int n0v = n0 - 512;
    __syncthreads();
    ushort_t (*T)[136] = (ushort_t(*)[136]) & smem[0][0][0];
#pragma unroll
    for (int mt = 0; mt < 4; ++mt)
#pragma unroll
      for (int nt = 0; nt < 4; ++nt)
#pragma unroll
        for (int r = 0; r < 4; ++r) {
          int n_l = wn * 64 + nt * 16 + l16;
          int m_l = wm * 64 + mt * 16 + quad * 4 + r;
          T[n_l][m_l] = f2bu(acc[mt][nt][r] + bv[n0v + n_l]);
        }
    __syncthreads();
    int row = tid >> 1, half = tid & 1;
    size_t gbase = (((size_t)bz * 8 + (n0v >> 6) + (row >> 6)) * 64 + (row & 63)) * 4096 +
                   m0 + half * 64;
    uint4* dst = (uint4*)(VTb + gbase);
    const uint4* src = (const uint4*)&T[row][half * 64];
#pragma unroll
    for (int j = 0; j < 8; ++j) dst[j] = src[j];
  }
}

// ---------------------------------------------------------------------------
// MFMA flash attention.
// Round-14 (T15): PV lags one chunk behind S. Iteration c computes S(c) and
// PV(c-1) — independent streams, so exp2(c) overlaps PV(c-1) MFMAs and
// S(c) MFMAs overlap the rest (the old S->exp2->PV serialization inside a
// chunk was the residual latency; all pipes were <31% busy). V is
// TRIPLE-buffered (hazard-checked: buf (c+1)%3 last read in iter c-1 before
// the barrier, written in iter c after it), K stays double-buffered.
// LDS 40 KB -> still exactly 4 blocks/CU. Single pa[2][2] reassigned per
// iter (SSA renaming, no copies, all compile-time indices). Accumulation
// order across chunks unchanged -> bit-identical numerics.
// Round-12 geometry kept: ct/nt-outer (16 b128 LDS reads/chunk, structural
// floor), key-bit-permuted V staging (S fragment IS the PV B-fragment),
// exp2 softmax (scale in Q), XOR bank swizzle, register prefetch.
// ---------------------------------------------------------------------------
template <int NS>
__global__ __launch_bounds__(256, 4) void attn_k(const BF* __restrict__ Q,
                                                 const BF* __restrict__ K,
                                                 const BF* __restrict__ VT,
                                                 BF* __restrict__ AO,
                                                 BF* __restrict__ Opart,
                                                 float* __restrict__ lpart) {
  __shared__ __align__(16) ushort_t Ks[2][64][64];
  __shared__ __align__(16) ushort_t VTs[3][64][64];

  const int tid = threadIdx.x;
  const int w = tid >> 6, lane = tid & 63;
  const int quad = lane >> 4, l16 = lane & 15;
  // Swizzle: element chunk c (16B) of row r lives at chunk c ^ (r & 7).
  const int r3 = l16 & 7;
  const int sc0 = (quad ^ r3) << 3;  // swizzled element col of orig chunk `quad`
  const int sc1 = sc0 ^ 32;          // orig chunk quad+4

  const int g = blockIdx.x;
  const int bh = g & 31;               // XCD = bh % 8 (K/V L2-pinned)
  const int qt = (g >> 5) & 7;
  const int ks = g >> 8;
  const int b = bh >> 3, h = bh & 7;
  const int q0 = qt * 128 + w * 32;
  const int kspan = 4096 / NS, kbase = ks * kspan;

  bf16x8 qa[2][2];
#pragma unroll
  for (int qs = 0; qs < 2; ++qs) {
    const BF* qp = Q + (((size_t)bh << 10) + q0 + qs * 16 + l16) * 64 + quad * 8;
    qa[qs][0] = *(const bf16x8*)qp;
    qa[qs][1] = *(const bf16x8*)(qp + 32);
  }
  bf16x8 ones;
#pragma unroll
  for (int j = 0; j < 8; ++j) ones[j] = (__bf16)1.0f;

  const BF* Kp = K + (size_t)bh * 4096 * 64;    // [key][dh]
  const BF* VTp = VT + (size_t)bh * 64 * 4096;  // [dh][key]

  f32x4 o[2][4] = {};
  f32x4 ol[2] = {};

  const int srow = tid >> 2, scol = (tid & 3) * 16;
  const int ssc = ((2 * (tid & 3)) ^ (srow & 7)) << 3;  // K swizzled store col
  // V store columns: key-bit-permuted + XOR-swizzled (see round-12 note).
  int vcol[4];
  {
    const int s1 = (tid >> 1) & 1, s0v = tid & 1;
#pragma unroll
    for (int gq = 0; gq < 4; ++gq)
      vcol[gq] = (((s1 * 4 + gq) ^ (srow & 7)) << 3) + s0v * 4;
  }

#define STAGE_V(buf, v0, v1)                                   \
  {                                                            \
    uint2 t_;                                                  \
    t_.x = (v0).x; t_.y = (v0).y; *(uint2*)&VTs[buf][srow][vcol[0]] = t_; \
    t_.x = (v0).z; t_.y = (v0).w; *(uint2*)&VTs[buf][srow][vcol[1]] = t_; \
    t_.x = (v1).x; t_.y = (v1).y; *(uint2*)&VTs[buf][srow][vcol[2]] = t_; \
    t_.x = (v1).z; t_.y = (v1).w; *(uint2*)&VTs[buf][srow][vcol[3]] = t_; \
  }

  {  // prologue: stage chunk 0 into K0/V0
    const uint4* kp = (const uint4*)(Kp + (size_t)(kbase + srow) * 64 + scol);
    const uint4* vp = (const uint4*)(VTp + (size_t)srow * 4096 + kbase + scol);
    uint4 a = kp[0], bb = kp[1], c = vp[0], d = vp[1];
    *(uint4*)&Ks[0][srow][ssc] = a;  *(uint4*)&Ks[0][srow][ssc ^ 8] = bb;
    STAGE_V(0, c, d);
  }
  __syncthreads();

  bf16x8 pa[2][2];  // P fragments of the most recent S-phase

  // S(c): Ks[KRD] x qa -> exp2 -> pa (packed PV B-fragments).
#define S_PHASE(KRD)                                                          \
  {                                                                           \
    unsigned pu[2][2][4];                                                     \
    _Pragma("unroll") for (int ct = 0; ct < 4; ++ct) {                        \
      const int krow = ct * 16 + l16;                                         \
      bf16x8 kb0 = *(const bf16x8*)&Ks[KRD][krow][sc0];                       \
      bf16x8 kb1 = *(const bf16x8*)&Ks[KRD][krow][sc1];                       \
      _Pragma("unroll") for (int qs = 0; qs < 2; ++qs) {                      \
        f32x4 s = {};                                                         \
        s = __builtin_amdgcn_mfma_f32_16x16x32_bf16(kb0, qa[qs][0], s, 0, 0, 0); \
        s = __builtin_amdgcn_mfma_f32_16x16x32_bf16(kb1, qa[qs][1], s, 0, 0, 0); \
        pu[qs][ct >> 1][(ct & 1) * 2] =                                       \
            pk2(__builtin_exp2f(s[0]), __builtin_exp2f(s[1]));                \
        pu[qs][ct >> 1][(ct & 1) * 2 + 1] =                                   \
            pk2(__builtin_exp2f(s[2]), __builtin_exp2f(s[3]));                \
      }                                                                       \
    }                                                                         \
    _Pragma("unroll") for (int qs = 0; qs < 2; ++qs)                          \
      _Pragma("unroll") for (int kk = 0; kk < 2; ++kk) {                      \
        uint4v u = {pu[qs][kk][0], pu[qs][kk][1], pu[qs][kk][2],              \
                    pu[qs][kk][3]};                                           \
        pa[qs][kk] = __builtin_bit_cast(bf16x8, u);                           \
      }                                                                       \
  }

  // PV: O^T += V^T P^T ; l += 1^T P^T using pa + VTs[VRD].
#define PV_PHASE(VRD)                                                         \
  {                                                                           \
    _Pragma("unroll") for (int qs = 0; qs < 2; ++qs) {                        \
      ol[qs] = __builtin_amdgcn_mfma_f32_16x16x32_bf16(ones, pa[qs][0], ol[qs], 0, 0, 0); \
      ol[qs] = __builtin_amdgcn_mfma_f32_16x16x32_bf16(ones, pa[qs][1], ol[qs], 0, 0, 0); \
    }                                                                         \
    _Pragma("unroll") for (int nt = 0; nt < 4; ++nt) {                        \
      const int vrow = nt * 16 + l16;                                         \
      bf16x8 vb0 = *(const bf16x8*)&VTs[VRD][vrow][sc0];                      \
      bf16x8 vb1 = *(const bf16x8*)&VTs[VRD][vrow][sc1];                      \
      _Pragma("unroll") for (int qs = 0; qs < 2; ++qs) {                      \
        o[qs][nt] = __builtin_amdgcn_mfma_f32_16x16x32_bf16(vb0, pa[qs][0], o[qs][nt], 0, 0, 0); \
        o[qs][nt] = __builtin_amdgcn_mfma_f32_16x16x32_bf16(vb1, pa[qs][1], o[qs][nt], 0, 0, 0); \
      }                                                                       \
    }                                                                         \
  }

  const int nc = kspan / 64;
  {  // iteration 0: S(0) only (no PV yet); stage chunk 1 -> K1/V1
    uint4 nk0, nk1, nv0, nv1;
    const bool more = (nc > 1);
    if (more) {
      const int c1 = kbase + 64;
      const uint4* kp = (const uint4*)(Kp + (size_t)(c1 + srow) * 64 + scol);
      const uint4* vp = (const uint4*)(VTp + (size_t)srow * 4096 + c1 + scol);
      nk0 = kp[0]; nk1 = kp[1]; nv0 = vp[0]; nv1 = vp[1];
    }
    __builtin_amdgcn_s_setprio(1);
    S_PHASE(0);
    __builtin_amdgcn_s_setprio(0);
    if (more) {
      *(uint4*)&Ks[1][srow][ssc] = nk0;
      *(uint4*)&Ks[1][srow][ssc ^ 8] = nk1;
      STAGE_V(1, nv0, nv1);
    }
    __syncthreads();
  }

  int krd = 1, vrd = 0, vwr = 2;
  for (int c = 1; c < nc; ++c) {
    uint4 nk0, nk1, nv0, nv1;
    const bool more = (c + 1 < nc);
    if (more) {  // issue next chunk's global loads early
      const int c1 = kbase + (c + 1) * 64;
      const uint4* kp = (const uint4*)(Kp + (size_t)(c1 + srow) * 64 + scol);
      const uint4* vp = (const uint4*)(VTp + (size_t)srow * 4096 + c1 + scol);
      nk0 = kp[0]; nk1 = kp[1]; nv0 = vp[0]; nv1 = vp[1];
    }
    __builtin_amdgcn_s_setprio(1);
    PV_PHASE(vrd);   // PV(c-1): uses pa from previous iteration
    S_PHASE(krd);    // S(c): overwrites pa (SSA-renamed, no copy)
    __builtin_amdgcn_s_setprio(0);
    if (more) {
      *(uint4*)&Ks[krd ^ 1][srow][ssc] = nk0;
      *(uint4*)&Ks[krd ^ 1][srow][ssc ^ 8] = nk1;
      STAGE_V(vwr, nv0, nv1);
    }
    __syncthreads();
    krd ^= 1;
    vrd = (vrd == 2) ? 0 : vrd + 1;
    vwr = (vwr == 2) ? 0 : vwr + 1;
  }
  PV_PHASE(vrd);  // final PV(nc-1); vrd == (nc-1)%3 here
#undef STAGE_V
#undef S_PHASE
#undef PV_PHASE

  // ---- epilogue: lane holds O^T[dh = nt*16+quad*4+r][q = l16] ----
#pragma unroll
  for (int qs = 0; qs < 2; ++qs) {
    int qg = q0 + qs * 16 + l16;
    if (NS == 1) {
      float invl = 1.f / ol[qs][0];
#pragma unroll
      for (int nt = 0; nt < 4; ++nt) {
        uint2 uu;
        uu.x = pk2(o[qs][nt][0] * invl, o[qs][nt][1] * invl);
        uu.y = pk2(o[qs][nt][2] * invl, o[qs][nt][3] * invl);
        *(uint2*)(AO + (((size_t)b << 10) + qg) * 512 + h * 64 + nt * 16 + quad * 4) = uu;
      }
    } else {
      if (quad == 0) lpart[ks * 32768 + (bh << 10) + qg] = ol[qs][0];
#pragma unroll
      for (int nt = 0; nt < 4; ++nt) {
        uint2 uu;
        uu.x = pk2(o[qs][nt][0], o[qs][nt][1]);
        uu.y = pk2(o[qs][nt][2], o[qs][nt][3]);
        *(uint2*)(Opart + (size_t)ks * 2097152 + (((size_t)bh << 10) + qg) * 64 +
                  nt * 16 + quad * 4) = uu;
      }
    }
  }
}

// ---------------------------------------------------------------------------
// gate_k: gate GEMM (K=1024, A=[local | AO]) + sigmoid-gate epilogue.
// NS-way K-split merge FUSED into A-staging. AO tile captured from LDS at
// k0==512+n0. Round-13: bf16 pre-converted local/Wg when present.
// ---------------------------------------------------------------------------
template <int NS>
__global__ __launch_bounds__(256) void gate_k(const float* __restrict__ local,
                                              const BF* __restrict__ localB,
                                              const BF* __restrict__ AO,
                                              const BF* __restrict__ Opart,
                                              const float* __restrict__ lpart,
                                              const float* __restrict__ Wg,
                                              const BF* __restrict__ WgB,
                                              const float* __restrict__ bg,
                                              BF* __restrict__ ENH) {
  __shared__ __align__(16) ushort_t As[64][72];
  __shared__ __align__(16) ushort_t Bs[64][72];
  const int tid = threadIdx.x;
  const int w = tid >> 6, lane = tid & 63;
  const int quad = lane >> 4, l16 = lane & 15;
  const int m0 = blockIdx.x * 64, n0 = blockIdx.y * 64;

  f32x4 acc[4] = {};
  float aosv[4][4];  // AO values for epilogue, captured from As
  for (int k0 = 0; k0 < 1024; k0 += 64) {
    __syncthreads();
    {
      int row = tid >> 2, cg = tid & 3;
      int kg = k0 + cg * 16;
      ushort_t vals[16];
      if (kg < 512) {
        if (localB) {
          const uint4* p = (const uint4*)(localB + (size_t)(m0 + row) * 512 + kg);
          *(uint4*)&vals[0] = p[0]; *(uint4*)&vals[8] = p[1];
        } else {
          rd16f(local + (size_t)(m0 + row) * 512 + kg, vals);
        }
      } else {
        int c = kg - 512;               // 16-aligned, single head per unit
        int hh = c >> 6, dh0 = c & 63;
        int mg = m0 + row;
        size_t bq = (size_t)(((mg >> 10) * 8 + hh) << 10) + (mg & 1023);
        if (NS == 1) {
          const uint4* p = (const uint4*)(AO + (size_t)mg * 512 + c);
          *(uint4*)&vals[0] = p[0]; *(uint4*)&vals[8] = p[1];
        } else {
          float ls = 0.f;
#pragma unroll
          for (int s2 = 0; s2 < NS; ++s2) ls += lpart[s2 * 32768 + bq];
          float inv = 1.f / ls;
          float av[16] = {};
#pragma unroll
          for (int s2 = 0; s2 < NS; ++s2) {
            const ushort_t* op = (const ushort_t*)Opart + (size_t)s2 * 2097152 +
                                 bq * 64 + dh0;
            uint4 u0 = ((const uint4*)op)[0], u1 = ((const uint4*)op)[1];
            const ushort_t* pu = (const ushort_t*)&u0;
#pragma unroll
            for (int j = 0; j < 8; ++j) av[j] += bu2f(pu[j]);
            pu = (const ushort_t*)&u1;
#pragma unroll
            for (int j = 0; j < 8; ++j) av[8 + j] += bu2f(pu[j]);
          }
#pragma unroll
          for (int j = 0; j < 16; j += 2)
            ((unsigned*)vals)[j / 2] = pk2(av[j] * inv, av[j + 1] * inv);
        }
      }
      *(uint4*)&As[row][cg * 16] = *(uint4*)&vals[0];
      *(uint4*)&As[row][cg * 16 + 8] = *(uint4*)&vals[8];
      if (WgB) {
        const uint4* p = (const uint4*)(WgB + (size_t)(n0 + row) * 1024 + kg);
        *(uint4*)&Bs[row][cg * 16] = p[0];
        *(uint4*)&Bs[row][cg * 16 + 8] = p[1];
      } else {
        ushort_t bv[16];
        rd16f(Wg + (size_t)(n0 + row) * 1024 + kg, bv);
        *(uint4*)&Bs[row][cg * 16] = *(uint4*)&bv[0];
        *(uint4*)&Bs[row][cg * 16 + 8] = *(uint4*)&bv[8];
      }
    }
    __syncthreads();
    if (k0 == 512 + n0) {  // capture this block's AO tile for the epilogue
#pragma unroll
      for (int r = 0; r < 4; ++r)
#pragma unroll
        for (int nt = 0; nt < 4; ++nt)
          aosv[r][nt] = bu2f(As[w * 16 + quad * 4 + r][nt * 16 + l16]);
    }
#pragma unroll
    for (int kc = 0; kc < 2; ++kc) {
      bf16x8 af = *(const bf16x8*)&As[w * 16 + l16][kc * 32 + quad * 8];
#pragma unroll
      for (int nt = 0; nt < 4; ++nt) {
        bf16x8 bfv = *(const bf16x8*)&Bs[nt * 16 + l16][kc * 32 + quad * 8];
        acc[nt] = __builtin_amdgcn_mfma_f32_16x16x32_bf16(af, bfv, acc[nt], 0, 0, 0);
      }
    }
  }
#pragma unroll
  for (int r = 0; r < 4; ++r) {
    int mg = m0 + w * 16 + quad * 4 + r;
#pragma unroll
    for (int nt = 0; nt < 4; ++nt) {
      int ng = n0 + nt * 16 + l16;
      size_t idx = (size_t)mg * 512 + ng;
      float gg = 1.f / (1.f + __expf(-(acc[nt][r] + bg[ng])));
      ENH[idx] = __float2bfloat16(local[idx] + gg * aosv[r][nt]);
    }
  }
}

// ---------------------------------------------------------------------------
// out_k: final projection, fp32 output.
// Round-13: B staging reads pre-converted bf16 WoB when present.
// ---------------------------------------------------------------------------
__global__ __launch_bounds__(256) void out_k(const BF* __restrict__ ENH,
                                             const float* __restrict__ Wo,
                                             const BF* __restrict__ WoB,
                                             const float* __restrict__ bo,
                                             float* __restrict__ out) {
  __shared__ __align__(16) ushort_t As[64][72];
  __shared__ __align__(16) ushort_t Bs[64][72];
  const int tid = threadIdx.x;
  const int w = tid >> 6, lane = tid & 63;
  const int quad = lane >> 4, l16 = lane & 15;
  const int m0 = blockIdx.x * 64, n0 = blockIdx.y * 64;

  f32x4 acc[4] = {};
  for (int k0 = 0; k0 < 512; k0 += 64) {
    __syncthreads();
    {
      int row = tid >> 2, cg = tid & 3;
      int kg = k0 + cg * 16;
      const uint4* p = (const uint4*)(ENH + (size_t)(m0 + row) * 512 + kg);
      *(uint4*)&As[row][cg * 16] = p[0];
      *(uint4*)&As[row][cg * 16 + 8] = p[1];
      if (WoB) {
        const uint4* pb = (const uint4*)(WoB + (size_t)(n0 + row) * 512 + kg);
        *(uint4*)&Bs[row][cg * 16] = pb[0];
        *(uint4*)&Bs[row][cg * 16 + 8] = pb[1];
      } else {
        ushort_t bv[16];
        rd16f(Wo + (size_t)(n0 + row) * 512 + kg, bv);
        *(uint4*)&Bs[row][cg * 16] = *(uint4*)&bv[0];
        *(uint4*)&Bs[row][cg * 16 + 8] = *(uint4*)&bv[8];
      }
    }
    __syncthreads();
#pragma unroll
    for (int kc = 0; kc < 2; ++kc) {
      bf16x8 af = *(const bf16x8*)&As[w * 16 + l16][kc * 32 + quad * 8];
#pragma unroll
      for (int nt = 0; nt < 4; ++nt) {
        bf16x8 bfv = *(const bf16x8*)&Bs[nt * 16 + l16][kc * 32 + quad * 8];
        acc[nt] = __builtin_amdgcn_mfma_f32_16x16x32_bf16(af, bfv, acc[nt], 0, 0, 0);
      }
    }
  }
#pragma unroll
  for (int r = 0; r < 4; ++r) {
    int mg = m0 + w * 16 + quad * 4 + r;
#pragma unroll
    for (int nt = 0; nt < 4; ++nt) {
      int ng = n0 + nt * 16 + l16;
      out[(size_t)mg * 512 + ng] = acc[nt][r] + bo[ng];
    }
  }
}

extern "C" void kernel_launch(void* const* d_in, const int* in_sizes, int n_in,
                              void* d_out, int out_size, void* d_ws, size_t ws_size,
                              hipStream_t stream) {
  const float* local = (const float*)d_in[0];
  const float* gfeat = (const float*)d_in[1];
  const float* Wq = (const float*)d_in[2];
  const float* bq = (const float*)d_in[3];
  const float* Wk = (const float*)d_in[4];
  const float* bk = (const float*)d_in[5];
  const float* Wv = (const float*)d_in[6];
  const float* bv = (const float*)d_in[7];
  const float* Wg = (const float*)d_in[8];
  const float* bg = (const float*)d_in[9];
  const float* Wo = (const float*)d_in[10];
  const float* bo = (const float*)d_in[11];

  char* w = (char*)d_ws;
  BF* Qb = (BF*)w;            w += (size_t)2097152 * 2;  // 4 MB (reused as ENH)
  BF* Kb = (BF*)w;            w += (size_t)8388608 * 2;  // 16 MB
  BF* VTb = (BF*)w;           w += (size_t)8388608 * 2;  // 16 MB (V^T [b,h,dh,key])
  BF* AO = (BF*)w;            w += (size_t)2097152 * 2;  // 4 MB (NS==1 only)
  // Region X: gfT (16 MB, dead after kv_k) aliases Opart (NS x 4 MB).
  BF* gfT = (BF*)w;
  BF* Opart = (BF*)w;
  size_t baseOff = (size_t)(w - (char*)d_ws);
  BF* ENH = Qb;

  int NS = 1;
  if (baseOff + 4 * (4194304 + 131072) <= ws_size) NS = 4;
  else if (baseOff + 16777216 + 2 * 131072 <= ws_size) NS = 2;
  float* lpart = (float*)(w + (size_t)NS * 4194304);

  // Round-13: bf16 prep region (weights 3 MB + localB 4 MB) after region X.
  size_t xsize = (size_t)NS * (4194304 + 131072);
  if (xsize < 16777216) xsize = 16777216;  // gfT aliases region X start
  BF* WB = (BF*)(w + xsize);
  BF* localB = WB + 1572864;
  bool useP = (baseOff + xsize + 3145728 + 4194304) <= ws_size;
  const BF *WqB = nullptr, *WkB = nullptr, *WvB = nullptr, *WgB = nullptr,
           *WoB = nullptr, *locB = nullptr;
  if (useP) {
    WqB = WB;            WkB = WB + 262144;  WvB = WB + 524288;
    WgB = WB + 786432;   WoB = WB + 1310720; locB = localB;
  }

  dim3 blk(256);
  if (useP)
    prep_k<<<dim3(896), blk, 0, stream>>>(local, Wq, Wk, Wv, Wg, Wo, localB, WB);
  pre_k<<<dim3(2560), blk, 0, stream>>>(local, gfeat, Wq, bq, locB, WqB, gfT, Qb);
  kv_k<<<dim3(1024), blk, 0, stream>>>(gfT, Wk, Wv, WkB, WvB, bk, bv, Kb, VTb);
  if (NS == 4) {
    attn_k<4><<<dim3(1024), blk, 0, stream>>>(Qb, Kb, VTb, AO, Opart, lpart);
    gate_k<4><<<dim3(64, 8), blk, 0, stream>>>(local, locB, AO, Opart, lpart, Wg, WgB, bg, ENH);
  } else if (NS == 2) {
    attn_k<2><<<dim3(512), blk, 0, stream>>>(Qb, Kb, VTb, AO, Opart, lpart);
    gate_k<2><<<dim3(64, 8), blk, 0, stream>>>(local, locB, AO, Opart, lpart, Wg, WgB, bg, ENH);
  } else {
    attn_k<1><<<dim3(256), blk, 0, stream>>>(Qb, Kb, VTb, AO, nullptr, nullptr);
    gate_k<1><<<dim3(64, 8), blk, 0, stream>>>(local, locB, AO, Opart, lpart, Wg, WgB, bg, ENH);
  }
  out_k<<<dim3(64, 8), blk, 0, stream>>>(ENH, Wo, WoB, bo, (float*)d_out);
}